// Round 13
// baseline (571.238 us; speedup 1.0000x reference)
//
#include <hip/hip_runtime.h>

#define KN 32768
#define KE 65536
#define KB 512
#define KEPB 64
#define KNREG 33
#define KEORD (KE + KNREG * KEPB)   /* 67648 padded sorted-edge slots */
#define KNBLK (KEORD / KEPB)        /* 1057 edge blocks */

/* ---------------- workspace element offsets ---------------- */
/* zero-init zone */
#define O_BUF0 ((size_t)0)
#define O_BUF1 (O_BUF0 + (size_t)KN * 64)
#define O_DEG  (O_BUF1 + (size_t)KN * 64)
#define O_GCNT (O_DEG + KN)
#define O_GST  (O_GCNT + KB)
#define O_HIST (O_GST + KB + 8)          /* [2][64] */
#define O_CUR  (O_HIST + 128)            /* [2][64] */
#define O_FLAG (O_CUR + 128)
#define O_ZEND (O_FLAG + 64)
/* -1-init zone */
#define O_EORD ((O_ZEND + 63) & ~(size_t)63)    /* [2][KEORD] */
#define O_RBLK (O_EORD + 2 * (size_t)KEORD)     /* [2][1088] */
#define O_FEND (O_RBLK + 2 * 1088)
/* no-init zone (fully written before read) */
#define O_WB   ((O_FEND + 63) & ~(size_t)63)    /* [33][4096] */
#define O_WS   (O_WB + (size_t)KNREG * 4096)
#define O_CROSS (O_WS + (size_t)KNREG * 4096)   /* [32] */
#define O_RCNT (O_CROSS + 64)
#define O_AOFF (O_RCNT + 64)                     /* [2][64] */
#define O_REGN (O_AOFF + 128)                    /* [E] */
#define O_END  (O_REGN + KE)

/* transposed LSTM weights: REUSE the eorder region (dead after conv loop;
   refilled every call -> replay-deterministic).
   Layout per matrix [256][K]: wT4[k4*256 + r] = float4(W[r][4k4..4k4+3]). */
#define T_WIH0 (O_EORD)             /* 256x128 = 32768 */
#define T_WHH0 (T_WIH0 + 32768)     /* 256x64  = 16384 */
#define T_WIH1 (T_WHH0 + 16384)
#define T_WHH1 (T_WIH1 + 16384)
#define T_WIH2 (T_WHH1 + 16384)
#define T_WHH2 (T_WIH2 + 16384)     /* end = O_EORD + 114688 <= O_RBLK */

__device__ float sigf(float x) { return 1.0f / (1.0f + expf(-x)); }

/* diagnostic fill (f32 output) */
extern "C" __global__ void GNNModule_9259949490279_kernel(float* out, float v) {
    int i = blockIdx.x * 256 + threadIdx.x;
    if (i < KB * 64) out[i] = v;
}

extern "C" __global__ void k_post(const int* flag, float* out) {
    int f = flag[0];
    if (f == 0) return;
    int i = blockIdx.x * 256 + threadIdx.x;
    if (i < KB * 64) out[i] = 300.0f + (float)f;
}

/* merged: zero-zone + (-1)-zone init in one launch */
extern "C" __global__ void k_init(float* wsf, int* wsi) {
    size_t i = (size_t)blockIdx.x * 256 + threadIdx.x;
    size_t stride = (size_t)gridDim.x * 256;
    for (size_t p = i; p < O_ZEND; p += stride) wsf[p] = 0.0f;
    for (size_t p = O_EORD + i; p < O_FEND; p += stride) wsi[p] = -1;
}

extern "C" __global__ void k_deg(const int* dst, float* deg, int* flag) {
    int e = blockIdx.x * 256 + threadIdx.x;
    if (e >= KE) return;
    int d = dst[e];
    if ((unsigned)d >= (unsigned)KN) { atomicOr(flag, 1); d = 0; }
    atomicAdd(&deg[d], 1.0f);
}

extern "C" __global__ void k_gcount(const int* gid, int* gcnt, int* flag) {
    int n = blockIdx.x * 256 + threadIdx.x;
    if (n >= KN) return;
    int g = gid[n];
    if ((unsigned)g >= (unsigned)KB) { atomicOr(flag, 2); g = 0; }
    atomicAdd(&gcnt[g], 1);
}

extern "C" __global__ void k_gscan(const int* gcnt, int* gstart) {
    __shared__ int part[64];
    __shared__ int pre[64];
    int t = threadIdx.x;
    int v[8];
    int s = 0;
    int base = t * 8;
    for (int j = 0; j < 8; ++j) { v[j] = gcnt[base + j]; s += v[j]; }
    part[t] = s;
    __syncthreads();
    if (t == 0) {
        int run = 0;
        for (int i = 0; i < 64; ++i) { pre[i] = run; run += part[i]; }
    }
    __syncthreads();
    int run = pre[t];
    for (int j = 0; j < 8; ++j) { gstart[base + j] = run; run += v[j]; }
    if (t == 63) gstart[KB] = run;
}

/* ---- region machinery: exact piecewise-linear edge MLP ---- */
extern "C" __global__ void k_prep(const float* ew1, const float* eb1,
                                  float* cross, int* rcnt) {
    if (threadIdx.x != 0 || blockIdx.x != 0) return;
    float cl[32];
    int n = 0;
    for (int k = 0; k < 32; ++k) {
        float a = ew1[k], b = eb1[k];
        if (a != 0.0f) {
            float tt = -b / a;
            if (tt > 0.0f && tt < 1.0f) cl[n++] = tt;
        }
    }
    for (int i = 1; i < n; ++i) {
        float v = cl[i];
        int j = i - 1;
        while (j >= 0 && cl[j] > v) { cl[j + 1] = cl[j]; --j; }
        cl[j + 1] = v;
    }
    for (int i = 0; i < n; ++i) cross[i] = cl[i];
    *rcnt = n;
}

extern "C" __global__ __launch_bounds__(256) void k_mats(
    const float* ew1, const float* eb1, const float* ew2, const float* eb2,
    const float* cross, const int* rcnt, float* Wb, float* Ws) {
    int r = blockIdx.x;
    int n = *rcnt;
    if (r > n) return;
    float lo = (r == 0) ? 0.0f : cross[r - 1];
    float hi = (r == n) ? 1.0f : cross[r];
    float mid = 0.5f * (lo + hi);
    __shared__ float mw[32], mb[32];
    int t = threadIdx.x;
    if (t < 32) {
        bool act = (mid * ew1[t] + eb1[t]) > 0.0f;
        mw[t] = act ? ew1[t] : 0.0f;
        mb[t] = act ? eb1[t] : 0.0f;
    }
    __syncthreads();
    #pragma unroll
    for (int j = 0; j < 16; ++j) {
        int idx = j * 256 + t;
        float as = 0.0f, ab = eb2[idx];
        #pragma unroll
        for (int k4 = 0; k4 < 8; ++k4) {
            float4 w2 = *(const float4*)&ew2[(size_t)idx * 32 + 4 * k4];
            as += mw[4*k4+0]*w2.x + mw[4*k4+1]*w2.y + mw[4*k4+2]*w2.z + mw[4*k4+3]*w2.w;
            ab += mb[4*k4+0]*w2.x + mb[4*k4+1]*w2.y + mb[4*k4+2]*w2.z + mb[4*k4+3]*w2.w;
        }
        Wb[(size_t)r * 4096 + idx] = ab;
        Ws[(size_t)r * 4096 + idx] = as;
    }
}

/* LDS histogram -> <=33 global atomics per block */
extern "C" __global__ void k_region(const float* ef, const float* cross,
                                    const int* rcnt, int* region, int* hist) {
    __shared__ float lcross[32];
    __shared__ int lh[64];
    __shared__ int ln;
    int t = threadIdx.x;
    if (t == 0) ln = *rcnt;
    if (t < 64) lh[t] = 0;
    if (t >= 32 && t < 64) lcross[t - 32] = 0.0f;
    __syncthreads();
    if (t < 32 && t < ln) lcross[t] = cross[t];
    __syncthreads();
    int e = blockIdx.x * 256 + t;
    float f = ef[e];
    int n = ln, r = 0;
    for (int j = 0; j < n; ++j) r += (f > lcross[j]) ? 1 : 0;
    region[e] = r;
    atomicAdd(&lh[r], 1);
    __syncthreads();
    if (t < 64 && lh[t] > 0) atomicAdd(&hist[t], lh[t]);
}

extern "C" __global__ void k_scan(const int* hist, const int* rcnt,
                                  int* aoff, int* rblk) {
    if (threadIdx.x != 0 || blockIdx.x != 0) return;
    int R = *rcnt + 1;
    int base = 0;
    for (int r = 0; r < R; ++r) {
        aoff[r] = base * KEPB;
        int nb = (hist[r] + KEPB - 1) / KEPB;
        for (int j = 0; j < nb; ++j) rblk[base + j] = r;
        base += nb;
    }
}

/* local LDS rank + one chunk-reserving global atomic per (block,region) */
extern "C" __global__ void k_scatidx(const int* region, const int* aoff,
                                     int* cursor, int* eorder) {
    __shared__ int lcnt[64];
    __shared__ int lbase[64];
    int t = threadIdx.x;
    if (t < 64) lcnt[t] = 0;
    __syncthreads();
    int e = blockIdx.x * 256 + t;
    int r = region[e];
    int lr = atomicAdd(&lcnt[r], 1);
    __syncthreads();
    if (t < 64 && lcnt[t] > 0) lbase[t] = atomicAdd(&cursor[t], lcnt[t]);
    __syncthreads();
    eorder[aoff[r] + lbase[r] + lr] = e;
}

/* ---- edge message + scatter (HW-verified round 9, kept verbatim) ---- */
extern "C" __global__ __launch_bounds__(256) void k_edge(
    const float* x, const float* efeat, const int* src, const int* dst,
    const float* Wb, const float* Ws, const int* rblk, const int* eorder,
    float* sbuf) {
    __shared__ __align__(16) float mbuf[4096];
    __shared__ __align__(16) float msuf[4096];
    __shared__ __align__(16) float xs[4][16][64];
    int b = blockIdx.x;
    int r = rblk[b];
    if (r < 0) return;
    int t = threadIdx.x;
    const float4* gb = (const float4*)(Wb + (size_t)r * 4096);
    const float4* gs = (const float4*)(Ws + (size_t)r * 4096);
    float4* lb = (float4*)mbuf;
    float4* ls = (float4*)msuf;
    #pragma unroll
    for (int j = 0; j < 4; ++j) {
        lb[t + 256 * j] = gb[t + 256 * j];
        ls[t + 256 * j] = gs[t + 256 * j];
    }
    __syncthreads();
    int w = t >> 6, lane = t & 63;
    int base = b * KEPB + w * 16;
    int eid = (lane < 16) ? eorder[base + lane] : -1;
    float efl = 0.0f;
    int srl = 0, dsl = 0;
    if (eid >= 0) { efl = efeat[eid]; srl = src[eid]; dsl = dst[eid]; }
    unsigned long long vm = __ballot(eid >= 0);
    if ((vm & 0xFFFFull) == 0ull) return;
    float ef[16];
    int dv[16];
    #pragma unroll
    for (int s = 0; s < 16; ++s) {
        ef[s] = __shfl(efl, s);
        int sv = __shfl(srl, s);
        dv[s] = __shfl(dsl, s);
        xs[w][s][lane] = x[(size_t)sv * 64 + lane];
    }
    float acc[16];
    #pragma unroll
    for (int s = 0; s < 16; ++s) acc[s] = 0.0f;
    #pragma unroll 1
    for (int i4 = 0; i4 < 16; ++i4) {
        float wb0 = mbuf[(i4 * 4 + 0) * 64 + lane], ws0 = msuf[(i4 * 4 + 0) * 64 + lane];
        float wb1 = mbuf[(i4 * 4 + 1) * 64 + lane], ws1 = msuf[(i4 * 4 + 1) * 64 + lane];
        float wb2 = mbuf[(i4 * 4 + 2) * 64 + lane], ws2 = msuf[(i4 * 4 + 2) * 64 + lane];
        float wb3 = mbuf[(i4 * 4 + 3) * 64 + lane], ws3 = msuf[(i4 * 4 + 3) * 64 + lane];
        #pragma unroll
        for (int j = 0; j < 16; ++j) {
            float4 xv = *(const float4*)&xs[w][j][i4 * 4];
            acc[j] = fmaf(xv.x, fmaf(ef[j], ws0, wb0), acc[j]);
            acc[j] = fmaf(xv.y, fmaf(ef[j], ws1, wb1), acc[j]);
            acc[j] = fmaf(xv.z, fmaf(ef[j], ws2, wb2), acc[j]);
            acc[j] = fmaf(xv.w, fmaf(ef[j], ws3, wb3), acc[j]);
        }
    }
    #pragma unroll
    for (int j = 0; j < 16; ++j) {
        if ((vm >> j) & 1ull) atomicAdd(&sbuf[(size_t)dv[j] * 64 + lane], acc[j]);
    }
}

extern "C" __global__ void k_final0(float* s, const float* deg, const float* cb, int* flag) {
    int idx = blockIdx.x * 256 + threadIdx.x;
    int n = idx >> 6;
    int o = idx & 63;
    float d = deg[n];
    if (d < 1.0f) d = 1.0f;
    float v = s[idx] / d + cb[o];
    if (v < 0.0f) v = 0.0f;
    if (!(v == v)) { v = 0.0f; atomicOr(flag, 32); }
    s[idx] = v;
}

extern "C" __global__ void k_final1ln(float* s, const float* deg, const float* cb,
                                      const float* lg, const float* lb, int* flag) {
    __shared__ float red[64];
    int t = threadIdx.x;
    int n = blockIdx.x;
    float d = deg[n];
    if (d < 1.0f) d = 1.0f;
    float v = s[(size_t)n * 64 + t] / d + cb[t];
    if (v < 0.0f) v = 0.0f;
    red[t] = v;
    __syncthreads();
    for (int m = 32; m >= 1; m >>= 1) {
        if (t < m) red[t] += red[t + m];
        __syncthreads();
    }
    float mu = red[0] * (1.0f / 64.0f);
    __syncthreads();
    red[t] = v * v;
    __syncthreads();
    for (int m = 32; m >= 1; m >>= 1) {
        if (t < m) red[t] += red[t + m];
        __syncthreads();
    }
    float var = red[0] * (1.0f / 64.0f) - mu * mu;
    float rs = rsqrtf(var + 1e-5f);
    float r = (v - mu) * rs * lg[t] + lb[t];
    if (!(r == r)) { r = 0.0f; atomicOr(flag, 8); }
    s[(size_t)n * 64 + t] = r;
}

/* one-time weight transpose into float4-column layout (R=256 always):
   dst[k4*256 + r] = float4(src[r][4k4 .. 4k4+3]) */
extern "C" __global__ void k_tw(const float* src, float4* dst, int K) {
    int idx = blockIdx.x * 256 + threadIdx.x;
    int total = 256 * (K >> 2);
    if (idx >= total) return;
    int r = idx & 255;
    int k4 = idx >> 8;
    const float* s = src + (size_t)r * K + 4 * k4;
    dst[idx] = make_float4(s[0], s[1], s[2], s[3]);
}

/* ---- Set2Set + head v3: 1 graph per 256-thread block (512 blocks, 2/CU);
   coalesced transposed weights; SINGLE-PASS online-softmax attention ---- */
extern "C" __global__ __launch_bounds__(256) void k_s2s3(
    const float* x, const int* gstart,
    const float4* wT0, const float4* uT0, const float* bih0, const float* bhh0,
    const float4* wT1, const float4* uT1, const float* bih1, const float* bhh1,
    const float4* wT2, const float4* uT2, const float* bih2, const float* bhh2,
    const float* gn_g, const float* gn_b,
    const float* fc1_w, const float* fc1_b,
    const float* bn_g, const float* bn_b, const float* bn_m, const float* bn_v,
    const float* fc2_w, const float* fc2_b,
    float* out, int* flag) {
    __shared__ __align__(16) float qs[128];
    __shared__ __align__(16) float hs0[64];
    __shared__ __align__(16) float hs1[64];
    __shared__ __align__(16) float hs2[64];
    __shared__ __align__(16) float cs[3][64];
    __shared__ __align__(16) float gat[256];
    __shared__ __align__(16) float red4[4][64];
    __shared__ float mz[4], zz[4];
    __shared__ __align__(16) float scr[128];
    int t = threadIdx.x;           /* 0..255 */
    int g = blockIdx.x;
    int wq = t >> 6, lane = t & 63;

    if (t < 128) qs[t] = 0.0f;
    if (t < 64) {
        hs0[t] = 0.0f; hs1[t] = 0.0f; hs2[t] = 0.0f;
        cs[0][t] = 0.0f; cs[1][t] = 0.0f; cs[2][t] = 0.0f;
    }
    __syncthreads();

    int n0 = gstart[g];
    int n1 = gstart[g + 1];
    if (n0 < 0) n0 = 0;
    if (n0 > KN) n0 = KN;
    if (n1 < n0) n1 = n0;
    if (n1 > KN) n1 = KN;
    int cnt = n1 - n0;
    if (cnt > 100000) cnt = 100000;

    for (int it = 0; it < 6; ++it) {
        /* layer 0: K=128 input qs */
        {
            float a = bih0[t] + bhh0[t];
            const float4* q4 = (const float4*)qs;
            #pragma unroll
            for (int k4 = 0; k4 < 32; ++k4) {
                float4 wv = wT0[k4 * 256 + t];
                float4 xv = q4[k4];
                a += wv.x*xv.x + wv.y*xv.y + wv.z*xv.z + wv.w*xv.w;
            }
            const float4* h4 = (const float4*)hs0;
            #pragma unroll
            for (int k4 = 0; k4 < 16; ++k4) {
                float4 wv = uT0[k4 * 256 + t];
                float4 hv = h4[k4];
                a += wv.x*hv.x + wv.y*hv.y + wv.z*hv.z + wv.w*hv.w;
            }
            gat[t] = a;
            __syncthreads();
            if (t < 64) {
                float c = sigf(gat[64 + t]) * cs[0][t] + sigf(gat[t]) * tanhf(gat[128 + t]);
                cs[0][t] = c;
                hs0[t] = sigf(gat[192 + t]) * tanhf(c);
            }
            __syncthreads();
        }
        /* layer 1 */
        {
            float a = bih1[t] + bhh1[t];
            const float4* i4 = (const float4*)hs0;
            const float4* h4 = (const float4*)hs1;
            #pragma unroll
            for (int k4 = 0; k4 < 16; ++k4) {
                float4 wv = wT1[k4 * 256 + t];
                float4 xv = i4[k4];
                a += wv.x*xv.x + wv.y*xv.y + wv.z*xv.z + wv.w*xv.w;
                float4 uv = uT1[k4 * 256 + t];
                float4 hv = h4[k4];
                a += uv.x*hv.x + uv.y*hv.y + uv.z*hv.z + uv.w*hv.w;
            }
            gat[t] = a;
            __syncthreads();
            if (t < 64) {
                float c = sigf(gat[64 + t]) * cs[1][t] + sigf(gat[t]) * tanhf(gat[128 + t]);
                cs[1][t] = c;
                hs1[t] = sigf(gat[192 + t]) * tanhf(c);
            }
            __syncthreads();
        }
        /* layer 2 */
        {
            float a = bih2[t] + bhh2[t];
            const float4* i4 = (const float4*)hs1;
            const float4* h4 = (const float4*)hs2;
            #pragma unroll
            for (int k4 = 0; k4 < 16; ++k4) {
                float4 wv = wT2[k4 * 256 + t];
                float4 xv = i4[k4];
                a += wv.x*xv.x + wv.y*xv.y + wv.z*xv.z + wv.w*xv.w;
                float4 uv = uT2[k4 * 256 + t];
                float4 hv = h4[k4];
                a += uv.x*hv.x + uv.y*hv.y + uv.z*hv.z + uv.w*hv.w;
            }
            gat[t] = a;
            __syncthreads();
            if (t < 64) {
                float c = sigf(gat[64 + t]) * cs[2][t] + sigf(gat[t]) * tanhf(gat[128 + t]);
                cs[2][t] = c;
                hs2[t] = sigf(gat[192 + t]) * tanhf(c);
            }
            __syncthreads();
        }
        /* single-pass online-softmax attention: per-wave (m,z,racc) */
        {
            float m = -3.0e38f, z = 0.0f, racc = 0.0f;
            float q = hs2[lane];
            for (int p = wq; p < cnt; p += 4) {
                float xv = x[(size_t)(n0 + p) * 64 + lane];
                float v = xv * q;
                v += __shfl_xor(v, 1);
                v += __shfl_xor(v, 2);
                v += __shfl_xor(v, 4);
                v += __shfl_xor(v, 8);
                v += __shfl_xor(v, 16);
                v += __shfl_xor(v, 32);
                if (v > m) {                 /* wave-uniform branch */
                    float sc = expf(m - v);  /* first row: exp(-inf)=0 */
                    z *= sc;
                    racc *= sc;
                    m = v;
                }
                float e = expf(v - m);
                z += e;
                racc += e * xv;
            }
            red4[wq][lane] = racc;
            if (lane == 0) { mz[wq] = m; zz[wq] = z; }
            __syncthreads();
            if (t < 64) {
                float M = mz[0];
                if (mz[1] > M) M = mz[1];
                if (mz[2] > M) M = mz[2];
                if (mz[3] > M) M = mz[3];
                float s0 = expf(mz[0] - M), s1 = expf(mz[1] - M);
                float s2 = expf(mz[2] - M), s3 = expf(mz[3] - M);
                float r = red4[0][t] * s0 + red4[1][t] * s1 + red4[2][t] * s2 + red4[3][t] * s3;
                float Z = zz[0] * s0 + zz[1] * s1 + zz[2] * s2 + zz[3] * s3;
                float rd = (cnt > 0 && Z > 0.0f) ? r / Z : 0.0f;
                qs[t] = hs2[t];
                qs[64 + t] = rd;
            }
            __syncthreads();
        }
    }

    /* head: graphnorm -> fc1 -> bn -> relu -> fc2 -> relu */
    float v = (t < 128) ? qs[t] : 0.0f;
    gat[t] = v;
    __syncthreads();
    for (int m = 128; m >= 1; m >>= 1) {
        if (t < m) gat[t] += gat[t + m];
        __syncthreads();
    }
    float mu = gat[0] * (1.0f / 128.0f);
    __syncthreads();
    gat[t] = v * v;
    __syncthreads();
    for (int m = 128; m >= 1; m >>= 1) {
        if (t < m) gat[t] += gat[t + m];
        __syncthreads();
    }
    float var = gat[0] * (1.0f / 128.0f) - mu * mu;
    float rs = rsqrtf(var + 1e-5f);
    if (t < 128) scr[t] = (v - mu) * rs * gn_g[t] + gn_b[t];
    __syncthreads();
    if (t < 128) {
        float y = fc1_b[t];
        const float4* wr = (const float4*)(fc1_w + (size_t)t * 128);
        #pragma unroll
        for (int k4 = 0; k4 < 32; ++k4) {
            float4 wv = wr[k4];
            float4 gv = *(const float4*)&scr[4 * k4];
            y += wv.x*gv.x + wv.y*gv.y + wv.z*gv.z + wv.w*gv.w;
        }
        y = (y - bn_m[t]) * rsqrtf(bn_v[t] + 1e-5f) * bn_g[t] + bn_b[t];
        if (y < 0.0f) y = 0.0f;
        gat[t] = y;
    }
    __syncthreads();
    if (t < 64) {
        float o = fc2_b[t];
        const float4* wr = (const float4*)(fc2_w + (size_t)t * 128);
        #pragma unroll
        for (int k4 = 0; k4 < 32; ++k4) {
            float4 wv = wr[k4];
            float4 yv = *(const float4*)&gat[4 * k4];
            o += wv.x*yv.x + wv.y*yv.y + wv.z*yv.z + wv.w*yv.w;
        }
        if (!(o == o)) o = 999.0f;
        else if (o < 0.0f) o = 0.0f;
        out[(size_t)g * 64 + t] = o;
    }
}

extern "C" void kernel_launch(void* const* d_in, const int* in_sizes, int n_in,
                              void* d_out, int out_size, void* d_ws, size_t ws_size,
                              hipStream_t stream) {
    float* out = (float*)d_out;
    const int outBlocks = (KB * 64 + 255) / 256;

    if (n_in != 39) {
        GNNModule_9259949490279_kernel<<<outBlocks, 256, 0, stream>>>(out, 50.0f);
        return;
    }
    if (in_sizes[0] != KN * 64 || in_sizes[1] != KE || in_sizes[4] != KN) {
        GNNModule_9259949490279_kernel<<<outBlocks, 256, 0, stream>>>(out, 60.0f);
        return;
    }
    if (out_size != KB * 64) {
        GNNModule_9259949490279_kernel<<<outBlocks, 256, 0, stream>>>(out, 80.0f);
        return;
    }
    if (ws_size < O_END * 4) {
        GNNModule_9259949490279_kernel<<<outBlocks, 256, 0, stream>>>(out, 100.0f);
        return;
    }

    const float* atom = (const float*)d_in[0];
    const float* efeat = (const float*)d_in[1];
    const int* src = (const int*)d_in[2];
    const int* dst = (const int*)d_in[3];
    const int* gid = (const int*)d_in[4];
    const float* ew1[2] = {(const float*)d_in[5], (const float*)d_in[10]};
    const float* eb1[2] = {(const float*)d_in[6], (const float*)d_in[11]};
    const float* ew2[2] = {(const float*)d_in[7], (const float*)d_in[12]};
    const float* eb2[2] = {(const float*)d_in[8], (const float*)d_in[13]};
    const float* cb[2] = {(const float*)d_in[9], (const float*)d_in[14]};
    const float* ln_g = (const float*)d_in[15];
    const float* ln_b = (const float*)d_in[16];
    const float* wih0 = (const float*)d_in[17];
    const float* whh0 = (const float*)d_in[18];
    const float* bih0 = (const float*)d_in[19];
    const float* bhh0 = (const float*)d_in[20];
    const float* wih1 = (const float*)d_in[21];
    const float* whh1 = (const float*)d_in[22];
    const float* bih1 = (const float*)d_in[23];
    const float* bhh1 = (const float*)d_in[24];
    const float* wih2 = (const float*)d_in[25];
    const float* whh2 = (const float*)d_in[26];
    const float* bih2 = (const float*)d_in[27];
    const float* bhh2 = (const float*)d_in[28];
    const float* gn_g = (const float*)d_in[29];
    const float* gn_b = (const float*)d_in[30];
    const float* fc1_w = (const float*)d_in[31];
    const float* fc1_b = (const float*)d_in[32];
    const float* bn_g = (const float*)d_in[33];
    const float* bn_b = (const float*)d_in[34];
    const float* bn_m = (const float*)d_in[35];
    const float* bn_v = (const float*)d_in[36];
    const float* fc2_w = (const float*)d_in[37];
    const float* fc2_b = (const float*)d_in[38];

    float* wsf = (float*)d_ws;
    int* wsi = (int*)d_ws;
    float* buf0 = wsf + O_BUF0;
    float* buf1 = wsf + O_BUF1;
    float* deg = wsf + O_DEG;
    int* gcnt = wsi + O_GCNT;
    int* gstart = wsi + O_GST;
    int* flag = wsi + O_FLAG;
    float* Wb = wsf + O_WB;
    float* Ws = wsf + O_WS;
    float* cross = wsf + O_CROSS;
    int* rcnt = wsi + O_RCNT;
    int* region = wsi + O_REGN;

    k_init<<<2048, 256, 0, stream>>>(wsf, wsi);

    k_deg<<<KE / 256, 256, 0, stream>>>(dst, deg, flag);
    k_gcount<<<KN / 256, 256, 0, stream>>>(gid, gcnt, flag);
    k_gscan<<<1, 64, 0, stream>>>(gcnt, gstart);

    for (int l = 0; l < 2; ++l) {
        const float* xin = (l == 0) ? atom : buf0;
        float* sout = (l == 0) ? buf0 : buf1;
        int* hist = wsi + O_HIST + l * 64;
        int* cursor = wsi + O_CUR + l * 64;
        int* aoff = wsi + O_AOFF + l * 64;
        int* eorder = wsi + O_EORD + l * KEORD;
        int* rblk = wsi + O_RBLK + l * 1088;

        k_prep<<<1, 64, 0, stream>>>(ew1[l], eb1[l], cross, rcnt);
        k_mats<<<KNREG, 256, 0, stream>>>(ew1[l], eb1[l], ew2[l], eb2[l], cross, rcnt, Wb, Ws);
        k_region<<<KE / 256, 256, 0, stream>>>(efeat, cross, rcnt, region, hist);
        k_scan<<<1, 64, 0, stream>>>(hist, rcnt, aoff, rblk);
        k_scatidx<<<KE / 256, 256, 0, stream>>>(region, aoff, cursor, eorder);
        k_edge<<<KNBLK, 256, 0, stream>>>(xin, efeat, src, dst, Wb, Ws, rblk, eorder, sout);
        if (l == 0) {
            k_final0<<<KN * 64 / 256, 256, 0, stream>>>(buf0, deg, cb[0], flag);
        } else {
            k_final1ln<<<KN, 64, 0, stream>>>(buf1, deg, cb[1], ln_g, ln_b, flag);
        }
    }

    /* transpose LSTM weights into the now-dead eorder region */
    float4* tw0 = (float4*)(wsf + T_WIH0);
    float4* tu0 = (float4*)(wsf + T_WHH0);
    float4* tw1 = (float4*)(wsf + T_WIH1);
    float4* tu1 = (float4*)(wsf + T_WHH1);
    float4* tw2 = (float4*)(wsf + T_WIH2);
    float4* tu2 = (float4*)(wsf + T_WHH2);
    k_tw<<<32, 256, 0, stream>>>(wih0, tw0, 128);
    k_tw<<<16, 256, 0, stream>>>(whh0, tu0, 64);
    k_tw<<<16, 256, 0, stream>>>(wih1, tw1, 64);
    k_tw<<<16, 256, 0, stream>>>(whh1, tu1, 64);
    k_tw<<<16, 256, 0, stream>>>(wih2, tw2, 64);
    k_tw<<<16, 256, 0, stream>>>(whh2, tu2, 64);

    k_s2s3<<<KB, 256, 0, stream>>>(buf1, gstart,
        tw0, tu0, bih0, bhh0,
        tw1, tu1, bih1, bhh1,
        tw2, tu2, bih2, bhh2,
        gn_g, gn_b, fc1_w, fc1_b, bn_g, bn_b, bn_m, bn_v, fc2_w, fc2_b,
        out, flag);

    k_post<<<outBlocks, 256, 0, stream>>>(flag, out);
}

// Round 14
// 516.859 us; speedup vs baseline: 1.1052x; 1.1052x over previous
//
#include <hip/hip_runtime.h>

#define KN 32768
#define KE 65536
#define KB 512
#define KEPB 64
#define KNREG 33
#define KEORD (KE + KNREG * KEPB)   /* 67648 padded sorted-edge slots */
#define KNBLK (KEORD / KEPB)        /* 1057 edge blocks */

/* ---------------- workspace element offsets ---------------- */
/* zero-init zone */
#define O_BUF0 ((size_t)0)
#define O_BUF1 (O_BUF0 + (size_t)KN * 64)
#define O_DEG  (O_BUF1 + (size_t)KN * 64)
#define O_GCNT (O_DEG + KN)
#define O_GST  (O_GCNT + KB)
#define O_HIST (O_GST + KB + 8)          /* [2][64] */
#define O_CUR  (O_HIST + 128)            /* [2][64] */
#define O_FLAG (O_CUR + 128)
#define O_ZEND (O_FLAG + 64)
/* -1-init zone */
#define O_EORD ((O_ZEND + 63) & ~(size_t)63)    /* [2][KEORD] */
#define O_RBLK (O_EORD + 2 * (size_t)KEORD)     /* [2][1088] */
#define O_FEND (O_RBLK + 2 * 1088)
/* no-init zone (fully written before read) */
#define O_WB   ((O_FEND + 63) & ~(size_t)63)    /* [33][4096] */
#define O_WS   (O_WB + (size_t)KNREG * 4096)
#define O_CROSS (O_WS + (size_t)KNREG * 4096)   /* [32] */
#define O_RCNT (O_CROSS + 64)
#define O_AOFF (O_RCNT + 64)                     /* [2][64] */
#define O_REGN (O_AOFF + 128)                    /* [E] */
#define O_END  (O_REGN + KE)

/* transposed LSTM weights in dead eorder region (refilled every call).
   Layout per matrix [256][K]: wT4[k4*256 + r] = float4(W[r][4k4..4k4+3]). */
#define T_WIH0 (O_EORD)             /* 256x128 = 32768 */
#define T_WHH0 (T_WIH0 + 32768)     /* 256x64  = 16384 */
#define T_WIH1 (T_WHH0 + 16384)
#define T_WHH1 (T_WIH1 + 16384)
#define T_WIH2 (T_WHH1 + 16384)
#define T_WHH2 (T_WIH2 + 16384)     /* end = O_EORD + 114688 <= O_RBLK */

__device__ float sigf(float x) { return 1.0f / (1.0f + expf(-x)); }

/* diagnostic fill (f32 output) */
extern "C" __global__ void GNNModule_9259949490279_kernel(float* out, float v) {
    int i = blockIdx.x * 256 + threadIdx.x;
    if (i < KB * 64) out[i] = v;
}

extern "C" __global__ void k_post(const int* flag, float* out) {
    int f = flag[0];
    if (f == 0) return;
    int i = blockIdx.x * 256 + threadIdx.x;
    if (i < KB * 64) out[i] = 300.0f + (float)f;
}

/* merged: zero-zone + (-1)-zone init in one launch */
extern "C" __global__ void k_init(float* wsf, int* wsi) {
    size_t i = (size_t)blockIdx.x * 256 + threadIdx.x;
    size_t stride = (size_t)gridDim.x * 256;
    for (size_t p = i; p < O_ZEND; p += stride) wsf[p] = 0.0f;
    for (size_t p = O_EORD + i; p < O_FEND; p += stride) wsi[p] = -1;
}

extern "C" __global__ void k_deg(const int* dst, float* deg, int* flag) {
    int e = blockIdx.x * 256 + threadIdx.x;
    if (e >= KE) return;
    int d = dst[e];
    if ((unsigned)d >= (unsigned)KN) { atomicOr(flag, 1); d = 0; }
    atomicAdd(&deg[d], 1.0f);
}

extern "C" __global__ void k_gcount(const int* gid, int* gcnt, int* flag) {
    int n = blockIdx.x * 256 + threadIdx.x;
    if (n >= KN) return;
    int g = gid[n];
    if ((unsigned)g >= (unsigned)KB) { atomicOr(flag, 2); g = 0; }
    atomicAdd(&gcnt[g], 1);
}

extern "C" __global__ void k_gscan(const int* gcnt, int* gstart) {
    __shared__ int part[64];
    __shared__ int pre[64];
    int t = threadIdx.x;
    int v[8];
    int s = 0;
    int base = t * 8;
    for (int j = 0; j < 8; ++j) { v[j] = gcnt[base + j]; s += v[j]; }
    part[t] = s;
    __syncthreads();
    if (t == 0) {
        int run = 0;
        for (int i = 0; i < 64; ++i) { pre[i] = run; run += part[i]; }
    }
    __syncthreads();
    int run = pre[t];
    for (int j = 0; j < 8; ++j) { gstart[base + j] = run; run += v[j]; }
    if (t == 63) gstart[KB] = run;
}

/* ---- region machinery: exact piecewise-linear edge MLP ---- */
extern "C" __global__ void k_prep(const float* ew1, const float* eb1,
                                  float* cross, int* rcnt) {
    if (threadIdx.x != 0 || blockIdx.x != 0) return;
    float cl[32];
    int n = 0;
    for (int k = 0; k < 32; ++k) {
        float a = ew1[k], b = eb1[k];
        if (a != 0.0f) {
            float tt = -b / a;
            if (tt > 0.0f && tt < 1.0f) cl[n++] = tt;
        }
    }
    for (int i = 1; i < n; ++i) {
        float v = cl[i];
        int j = i - 1;
        while (j >= 0 && cl[j] > v) { cl[j + 1] = cl[j]; --j; }
        cl[j + 1] = v;
    }
    for (int i = 0; i < n; ++i) cross[i] = cl[i];
    *rcnt = n;
}

extern "C" __global__ __launch_bounds__(256) void k_mats(
    const float* ew1, const float* eb1, const float* ew2, const float* eb2,
    const float* cross, const int* rcnt, float* Wb, float* Ws) {
    int r = blockIdx.x;
    int n = *rcnt;
    if (r > n) return;
    float lo = (r == 0) ? 0.0f : cross[r - 1];
    float hi = (r == n) ? 1.0f : cross[r];
    float mid = 0.5f * (lo + hi);
    __shared__ float mw[32], mb[32];
    int t = threadIdx.x;
    if (t < 32) {
        bool act = (mid * ew1[t] + eb1[t]) > 0.0f;
        mw[t] = act ? ew1[t] : 0.0f;
        mb[t] = act ? eb1[t] : 0.0f;
    }
    __syncthreads();
    #pragma unroll
    for (int j = 0; j < 16; ++j) {
        int idx = j * 256 + t;
        float as = 0.0f, ab = eb2[idx];
        #pragma unroll
        for (int k4 = 0; k4 < 8; ++k4) {
            float4 w2 = *(const float4*)&ew2[(size_t)idx * 32 + 4 * k4];
            as += mw[4*k4+0]*w2.x + mw[4*k4+1]*w2.y + mw[4*k4+2]*w2.z + mw[4*k4+3]*w2.w;
            ab += mb[4*k4+0]*w2.x + mb[4*k4+1]*w2.y + mb[4*k4+2]*w2.z + mb[4*k4+3]*w2.w;
        }
        Wb[(size_t)r * 4096 + idx] = ab;
        Ws[(size_t)r * 4096 + idx] = as;
    }
}

/* LDS histogram -> <=33 global atomics per block */
extern "C" __global__ void k_region(const float* ef, const float* cross,
                                    const int* rcnt, int* region, int* hist) {
    __shared__ float lcross[32];
    __shared__ int lh[64];
    __shared__ int ln;
    int t = threadIdx.x;
    if (t == 0) ln = *rcnt;
    if (t < 64) lh[t] = 0;
    if (t >= 32 && t < 64) lcross[t - 32] = 0.0f;
    __syncthreads();
    if (t < 32 && t < ln) lcross[t] = cross[t];
    __syncthreads();
    int e = blockIdx.x * 256 + t;
    float f = ef[e];
    int n = ln, r = 0;
    for (int j = 0; j < n; ++j) r += (f > lcross[j]) ? 1 : 0;
    region[e] = r;
    atomicAdd(&lh[r], 1);
    __syncthreads();
    if (t < 64 && lh[t] > 0) atomicAdd(&hist[t], lh[t]);
}

extern "C" __global__ void k_scan(const int* hist, const int* rcnt,
                                  int* aoff, int* rblk) {
    if (threadIdx.x != 0 || blockIdx.x != 0) return;
    int R = *rcnt + 1;
    int base = 0;
    for (int r = 0; r < R; ++r) {
        aoff[r] = base * KEPB;
        int nb = (hist[r] + KEPB - 1) / KEPB;
        for (int j = 0; j < nb; ++j) rblk[base + j] = r;
        base += nb;
    }
}

/* local LDS rank + one chunk-reserving global atomic per (block,region) */
extern "C" __global__ void k_scatidx(const int* region, const int* aoff,
                                     int* cursor, int* eorder) {
    __shared__ int lcnt[64];
    __shared__ int lbase[64];
    int t = threadIdx.x;
    if (t < 64) lcnt[t] = 0;
    __syncthreads();
    int e = blockIdx.x * 256 + t;
    int r = region[e];
    int lr = atomicAdd(&lcnt[r], 1);
    __syncthreads();
    if (t < 64 && lcnt[t] > 0) lbase[t] = atomicAdd(&cursor[t], lcnt[t]);
    __syncthreads();
    eorder[aoff[r] + lbase[r] + lr] = e;
}

/* ---- edge message + scatter (HW-verified round 9, kept verbatim) ---- */
extern "C" __global__ __launch_bounds__(256) void k_edge(
    const float* x, const float* efeat, const int* src, const int* dst,
    const float* Wb, const float* Ws, const int* rblk, const int* eorder,
    float* sbuf) {
    __shared__ __align__(16) float mbuf[4096];
    __shared__ __align__(16) float msuf[4096];
    __shared__ __align__(16) float xs[4][16][64];
    int b = blockIdx.x;
    int r = rblk[b];
    if (r < 0) return;
    int t = threadIdx.x;
    const float4* gb = (const float4*)(Wb + (size_t)r * 4096);
    const float4* gs = (const float4*)(Ws + (size_t)r * 4096);
    float4* lb = (float4*)mbuf;
    float4* ls = (float4*)msuf;
    #pragma unroll
    for (int j = 0; j < 4; ++j) {
        lb[t + 256 * j] = gb[t + 256 * j];
        ls[t + 256 * j] = gs[t + 256 * j];
    }
    __syncthreads();
    int w = t >> 6, lane = t & 63;
    int base = b * KEPB + w * 16;
    int eid = (lane < 16) ? eorder[base + lane] : -1;
    float efl = 0.0f;
    int srl = 0, dsl = 0;
    if (eid >= 0) { efl = efeat[eid]; srl = src[eid]; dsl = dst[eid]; }
    unsigned long long vm = __ballot(eid >= 0);
    if ((vm & 0xFFFFull) == 0ull) return;
    float ef[16];
    int dv[16];
    #pragma unroll
    for (int s = 0; s < 16; ++s) {
        ef[s] = __shfl(efl, s);
        int sv = __shfl(srl, s);
        dv[s] = __shfl(dsl, s);
        xs[w][s][lane] = x[(size_t)sv * 64 + lane];
    }
    float acc[16];
    #pragma unroll
    for (int s = 0; s < 16; ++s) acc[s] = 0.0f;
    #pragma unroll 1
    for (int i4 = 0; i4 < 16; ++i4) {
        float wb0 = mbuf[(i4 * 4 + 0) * 64 + lane], ws0 = msuf[(i4 * 4 + 0) * 64 + lane];
        float wb1 = mbuf[(i4 * 4 + 1) * 64 + lane], ws1 = msuf[(i4 * 4 + 1) * 64 + lane];
        float wb2 = mbuf[(i4 * 4 + 2) * 64 + lane], ws2 = msuf[(i4 * 4 + 2) * 64 + lane];
        float wb3 = mbuf[(i4 * 4 + 3) * 64 + lane], ws3 = msuf[(i4 * 4 + 3) * 64 + lane];
        #pragma unroll
        for (int j = 0; j < 16; ++j) {
            float4 xv = *(const float4*)&xs[w][j][i4 * 4];
            acc[j] = fmaf(xv.x, fmaf(ef[j], ws0, wb0), acc[j]);
            acc[j] = fmaf(xv.y, fmaf(ef[j], ws1, wb1), acc[j]);
            acc[j] = fmaf(xv.z, fmaf(ef[j], ws2, wb2), acc[j]);
            acc[j] = fmaf(xv.w, fmaf(ef[j], ws3, wb3), acc[j]);
        }
    }
    #pragma unroll
    for (int j = 0; j < 16; ++j) {
        if ((vm >> j) & 1ull) atomicAdd(&sbuf[(size_t)dv[j] * 64 + lane], acc[j]);
    }
}

extern "C" __global__ void k_final0(float* s, const float* deg, const float* cb, int* flag) {
    int idx = blockIdx.x * 256 + threadIdx.x;
    int n = idx >> 6;
    int o = idx & 63;
    float d = deg[n];
    if (d < 1.0f) d = 1.0f;
    float v = s[idx] / d + cb[o];
    if (v < 0.0f) v = 0.0f;
    if (!(v == v)) { v = 0.0f; atomicOr(flag, 32); }
    s[idx] = v;
}

extern "C" __global__ void k_final1ln(float* s, const float* deg, const float* cb,
                                      const float* lg, const float* lb, int* flag) {
    __shared__ float red[64];
    int t = threadIdx.x;
    int n = blockIdx.x;
    float d = deg[n];
    if (d < 1.0f) d = 1.0f;
    float v = s[(size_t)n * 64 + t] / d + cb[t];
    if (v < 0.0f) v = 0.0f;
    red[t] = v;
    __syncthreads();
    for (int m = 32; m >= 1; m >>= 1) {
        if (t < m) red[t] += red[t + m];
        __syncthreads();
    }
    float mu = red[0] * (1.0f / 64.0f);
    __syncthreads();
    red[t] = v * v;
    __syncthreads();
    for (int m = 32; m >= 1; m >>= 1) {
        if (t < m) red[t] += red[t + m];
        __syncthreads();
    }
    float var = red[0] * (1.0f / 64.0f) - mu * mu;
    float rs = rsqrtf(var + 1e-5f);
    float r = (v - mu) * rs * lg[t] + lb[t];
    if (!(r == r)) { r = 0.0f; atomicOr(flag, 8); }
    s[(size_t)n * 64 + t] = r;
}

/* one-time weight transpose into float4-column layout (R=256 always):
   dst[k4*256 + r] = float4(src[r][4k4 .. 4k4+3]) */
extern "C" __global__ void k_tw(const float* src, float4* dst, int K) {
    int idx = blockIdx.x * 256 + threadIdx.x;
    int total = 256 * (K >> 2);
    if (idx >= total) return;
    int r = idx & 255;
    int k4 = idx >> 8;
    const float* s = src + (size_t)r * K + 4 * k4;
    dst[idx] = make_float4(s[0], s[1], s[2], s[3]);
}

/* ---- Set2Set + head v4: round-11 structure (512 blocks x 256 thr, two-pass
   attention) with ONLY the weight loads switched to coalesced transposed ---- */
extern "C" __global__ __launch_bounds__(256) void k_s2s4(
    const float* x, const int* gstart,
    const float4* wT0, const float4* uT0, const float* bih0, const float* bhh0,
    const float4* wT1, const float4* uT1, const float* bih1, const float* bhh1,
    const float4* wT2, const float4* uT2, const float* bih2, const float* bhh2,
    const float* gn_g, const float* gn_b,
    const float* fc1_w, const float* fc1_b,
    const float* bn_g, const float* bn_b, const float* bn_m, const float* bn_v,
    const float* fc2_w, const float* fc2_b,
    float* out, int* flag) {
    __shared__ __align__(16) float qs[128];
    __shared__ __align__(16) float hs0[64];
    __shared__ __align__(16) float hs1[64];
    __shared__ __align__(16) float hs2[64];
    __shared__ __align__(16) float cs[3][64];
    __shared__ __align__(16) float gat[256];
    __shared__ __align__(16) float esc[1024];
    __shared__ __align__(16) float red4[4][64];
    __shared__ __align__(16) float scr[128];
    int t = threadIdx.x;           /* 0..255 */
    int g = blockIdx.x;
    int w = t >> 6, lane = t & 63;

    if (t < 128) qs[t] = 0.0f;
    if (t < 64) {
        hs0[t] = 0.0f; hs1[t] = 0.0f; hs2[t] = 0.0f;
        cs[0][t] = 0.0f; cs[1][t] = 0.0f; cs[2][t] = 0.0f;
    }
    __syncthreads();

    int n0 = gstart[g];
    int n1 = gstart[g + 1];
    if (n0 < 0) n0 = 0;
    if (n0 > KN) n0 = KN;
    if (n1 < n0) n1 = n0;
    if (n1 > KN) n1 = KN;
    int cnt = n1 - n0;
    if (cnt > 1024) { cnt = 1024; if (t == 0) atomicOr(flag, 16); }

    for (int it = 0; it < 6; ++it) {
        /* layer 0: K=128, input qs; coalesced wT0[k4*256+t] */
        {
            float a = bih0[t] + bhh0[t];
            const float4* q4 = (const float4*)qs;
            #pragma unroll
            for (int k4 = 0; k4 < 32; ++k4) {
                float4 wv = wT0[k4 * 256 + t];
                float4 xv = q4[k4];
                a += wv.x*xv.x + wv.y*xv.y + wv.z*xv.z + wv.w*xv.w;
            }
            const float4* h4 = (const float4*)hs0;
            #pragma unroll
            for (int k4 = 0; k4 < 16; ++k4) {
                float4 wv = uT0[k4 * 256 + t];
                float4 hv = h4[k4];
                a += wv.x*hv.x + wv.y*hv.y + wv.z*hv.z + wv.w*hv.w;
            }
            gat[t] = a;
            __syncthreads();
            if (t < 64) {
                float c = sigf(gat[64 + t]) * cs[0][t] + sigf(gat[t]) * tanhf(gat[128 + t]);
                cs[0][t] = c;
                hs0[t] = sigf(gat[192 + t]) * tanhf(c);
            }
            __syncthreads();
        }
        /* layer 1 */
        {
            float a = bih1[t] + bhh1[t];
            const float4* i4 = (const float4*)hs0;
            const float4* h4 = (const float4*)hs1;
            #pragma unroll
            for (int k4 = 0; k4 < 16; ++k4) {
                float4 wv = wT1[k4 * 256 + t];
                float4 xv = i4[k4];
                a += wv.x*xv.x + wv.y*xv.y + wv.z*xv.z + wv.w*xv.w;
                float4 uv = uT1[k4 * 256 + t];
                float4 hv = h4[k4];
                a += uv.x*hv.x + uv.y*hv.y + uv.z*hv.z + uv.w*hv.w;
            }
            gat[t] = a;
            __syncthreads();
            if (t < 64) {
                float c = sigf(gat[64 + t]) * cs[1][t] + sigf(gat[t]) * tanhf(gat[128 + t]);
                cs[1][t] = c;
                hs1[t] = sigf(gat[192 + t]) * tanhf(c);
            }
            __syncthreads();
        }
        /* layer 2 */
        {
            float a = bih2[t] + bhh2[t];
            const float4* i4 = (const float4*)hs1;
            const float4* h4 = (const float4*)hs2;
            #pragma unroll
            for (int k4 = 0; k4 < 16; ++k4) {
                float4 wv = wT2[k4 * 256 + t];
                float4 xv = i4[k4];
                a += wv.x*xv.x + wv.y*xv.y + wv.z*xv.z + wv.w*xv.w;
                float4 uv = uT2[k4 * 256 + t];
                float4 hv = h4[k4];
                a += uv.x*hv.x + uv.y*hv.y + uv.z*hv.z + uv.w*hv.w;
            }
            gat[t] = a;
            __syncthreads();
            if (t < 64) {
                float c = sigf(gat[64 + t]) * cs[2][t] + sigf(gat[t]) * tanhf(gat[128 + t]);
                cs[2][t] = c;
                hs2[t] = sigf(gat[192 + t]) * tanhf(c);
            }
            __syncthreads();
        }
        /* attention: scores over 256 threads (independent rows) */
        float mx = -1e30f;
        for (int p = t; p < cnt; p += 256) {
            const float* xr = x + (size_t)(n0 + p) * 64;
            float a = 0.0f;
            #pragma unroll
            for (int k4 = 0; k4 < 16; ++k4) {
                float4 xv = *(const float4*)&xr[4 * k4];
                float4 qv = *(const float4*)&hs2[4 * k4];
                a += xv.x*qv.x + xv.y*qv.y + xv.z*qv.z + xv.w*qv.w;
            }
            esc[p] = a;
            if (a > mx) mx = a;
        }
        gat[t] = mx;
        __syncthreads();
        for (int m = 128; m >= 1; m >>= 1) {
            if (t < m) { if (gat[t + m] > gat[t]) gat[t] = gat[t + m]; }
            __syncthreads();
        }
        mx = gat[0];
        __syncthreads();
        float z = 0.0f;
        for (int p = t; p < cnt; p += 256) {
            float a = expf(esc[p] - mx);
            esc[p] = a;
            z += a;
        }
        gat[t] = z;
        __syncthreads();
        for (int m = 128; m >= 1; m >>= 1) {
            if (t < m) gat[t] += gat[t + m];
            __syncthreads();
        }
        z = gat[0];
        float rz = (cnt > 0) ? 1.0f / z : 0.0f;
        /* readout: wave w handles rows p = w, w+4, ... (coalesced) */
        float rd = 0.0f;
        for (int p = w; p < cnt; p += 4)
            rd += x[(size_t)(n0 + p) * 64 + lane] * esc[p];
        red4[w][lane] = rd;
        __syncthreads();
        if (t < 64) {
            float r = (red4[0][t] + red4[1][t] + red4[2][t] + red4[3][t]) * rz;
            qs[t] = hs2[t];
            qs[64 + t] = r;
        }
        __syncthreads();
    }

    /* head: graphnorm -> fc1 -> bn -> relu -> fc2 -> relu */
    float v = (t < 128) ? qs[t] : 0.0f;
    gat[t] = v;
    __syncthreads();
    for (int m = 128; m >= 1; m >>= 1) {
        if (t < m) gat[t] += gat[t + m];
        __syncthreads();
    }
    float mu = gat[0] * (1.0f / 128.0f);
    __syncthreads();
    gat[t] = v * v;
    __syncthreads();
    for (int m = 128; m >= 1; m >>= 1) {
        if (t < m) gat[t] += gat[t + m];
        __syncthreads();
    }
    float var = gat[0] * (1.0f / 128.0f) - mu * mu;
    float rs = rsqrtf(var + 1e-5f);
    if (t < 128) scr[t] = (v - mu) * rs * gn_g[t] + gn_b[t];
    __syncthreads();
    if (t < 128) {
        float y = fc1_b[t];
        const float4* wr = (const float4*)(fc1_w + (size_t)t * 128);
        #pragma unroll
        for (int k4 = 0; k4 < 32; ++k4) {
            float4 wv = wr[k4];
            float4 gv = *(const float4*)&scr[4 * k4];
            y += wv.x*gv.x + wv.y*gv.y + wv.z*gv.z + wv.w*gv.w;
        }
        y = (y - bn_m[t]) * rsqrtf(bn_v[t] + 1e-5f) * bn_g[t] + bn_b[t];
        if (y < 0.0f) y = 0.0f;
        esc[t] = y;
    }
    __syncthreads();
    if (t < 64) {
        float o = fc2_b[t];
        const float4* wr = (const float4*)(fc2_w + (size_t)t * 128);
        #pragma unroll
        for (int k4 = 0; k4 < 32; ++k4) {
            float4 wv = wr[k4];
            float4 yv = *(const float4*)&esc[4 * k4];
            o += wv.x*yv.x + wv.y*yv.y + wv.z*yv.z + wv.w*yv.w;
        }
        if (!(o == o)) o = 999.0f;
        else if (o < 0.0f) o = 0.0f;
        out[(size_t)g * 64 + t] = o;
    }
}

extern "C" void kernel_launch(void* const* d_in, const int* in_sizes, int n_in,
                              void* d_out, int out_size, void* d_ws, size_t ws_size,
                              hipStream_t stream) {
    float* out = (float*)d_out;
    const int outBlocks = (KB * 64 + 255) / 256;

    if (n_in != 39) {
        GNNModule_9259949490279_kernel<<<outBlocks, 256, 0, stream>>>(out, 50.0f);
        return;
    }
    if (in_sizes[0] != KN * 64 || in_sizes[1] != KE || in_sizes[4] != KN) {
        GNNModule_9259949490279_kernel<<<outBlocks, 256, 0, stream>>>(out, 60.0f);
        return;
    }
    if (out_size != KB * 64) {
        GNNModule_9259949490279_kernel<<<outBlocks, 256, 0, stream>>>(out, 80.0f);
        return;
    }
    if (ws_size < O_END * 4) {
        GNNModule_9259949490279_kernel<<<outBlocks, 256, 0, stream>>>(out, 100.0f);
        return;
    }

    const float* atom = (const float*)d_in[0];
    const float* efeat = (const float*)d_in[1];
    const int* src = (const int*)d_in[2];
    const int* dst = (const int*)d_in[3];
    const int* gid = (const int*)d_in[4];
    const float* ew1[2] = {(const float*)d_in[5], (const float*)d_in[10]};
    const float* eb1[2] = {(const float*)d_in[6], (const float*)d_in[11]};
    const float* ew2[2] = {(const float*)d_in[7], (const float*)d_in[12]};
    const float* eb2[2] = {(const float*)d_in[8], (const float*)d_in[13]};
    const float* cb[2] = {(const float*)d_in[9], (const float*)d_in[14]};
    const float* ln_g = (const float*)d_in[15];
    const float* ln_b = (const float*)d_in[16];
    const float* wih0 = (const float*)d_in[17];
    const float* whh0 = (const float*)d_in[18];
    const float* bih0 = (const float*)d_in[19];
    const float* bhh0 = (const float*)d_in[20];
    const float* wih1 = (const float*)d_in[21];
    const float* whh1 = (const float*)d_in[22];
    const float* bih1 = (const float*)d_in[23];
    const float* bhh1 = (const float*)d_in[24];
    const float* wih2 = (const float*)d_in[25];
    const float* whh2 = (const float*)d_in[26];
    const float* bih2 = (const float*)d_in[27];
    const float* bhh2 = (const float*)d_in[28];
    const float* gn_g = (const float*)d_in[29];
    const float* gn_b = (const float*)d_in[30];
    const float* fc1_w = (const float*)d_in[31];
    const float* fc1_b = (const float*)d_in[32];
    const float* bn_g = (const float*)d_in[33];
    const float* bn_b = (const float*)d_in[34];
    const float* bn_m = (const float*)d_in[35];
    const float* bn_v = (const float*)d_in[36];
    const float* fc2_w = (const float*)d_in[37];
    const float* fc2_b = (const float*)d_in[38];

    float* wsf = (float*)d_ws;
    int* wsi = (int*)d_ws;
    float* buf0 = wsf + O_BUF0;
    float* buf1 = wsf + O_BUF1;
    float* deg = wsf + O_DEG;
    int* gcnt = wsi + O_GCNT;
    int* gstart = wsi + O_GST;
    int* flag = wsi + O_FLAG;
    float* Wb = wsf + O_WB;
    float* Ws = wsf + O_WS;
    float* cross = wsf + O_CROSS;
    int* rcnt = wsi + O_RCNT;
    int* region = wsi + O_REGN;

    k_init<<<2048, 256, 0, stream>>>(wsf, wsi);

    k_deg<<<KE / 256, 256, 0, stream>>>(dst, deg, flag);
    k_gcount<<<KN / 256, 256, 0, stream>>>(gid, gcnt, flag);
    k_gscan<<<1, 64, 0, stream>>>(gcnt, gstart);

    for (int l = 0; l < 2; ++l) {
        const float* xin = (l == 0) ? atom : buf0;
        float* sout = (l == 0) ? buf0 : buf1;
        int* hist = wsi + O_HIST + l * 64;
        int* cursor = wsi + O_CUR + l * 64;
        int* aoff = wsi + O_AOFF + l * 64;
        int* eorder = wsi + O_EORD + l * KEORD;
        int* rblk = wsi + O_RBLK + l * 1088;

        k_prep<<<1, 64, 0, stream>>>(ew1[l], eb1[l], cross, rcnt);
        k_mats<<<KNREG, 256, 0, stream>>>(ew1[l], eb1[l], ew2[l], eb2[l], cross, rcnt, Wb, Ws);
        k_region<<<KE / 256, 256, 0, stream>>>(efeat, cross, rcnt, region, hist);
        k_scan<<<1, 64, 0, stream>>>(hist, rcnt, aoff, rblk);
        k_scatidx<<<KE / 256, 256, 0, stream>>>(region, aoff, cursor, eorder);
        k_edge<<<KNBLK, 256, 0, stream>>>(xin, efeat, src, dst, Wb, Ws, rblk, eorder, sout);
        if (l == 0) {
            k_final0<<<KN * 64 / 256, 256, 0, stream>>>(buf0, deg, cb[0], flag);
        } else {
            k_final1ln<<<KN, 64, 0, stream>>>(buf1, deg, cb[1], ln_g, ln_b, flag);
        }
    }

    /* transpose LSTM weights into the now-dead eorder region */
    float4* tw0 = (float4*)(wsf + T_WIH0);
    float4* tu0 = (float4*)(wsf + T_WHH0);
    float4* tw1 = (float4*)(wsf + T_WIH1);
    float4* tu1 = (float4*)(wsf + T_WHH1);
    float4* tw2 = (float4*)(wsf + T_WIH2);
    float4* tu2 = (float4*)(wsf + T_WHH2);
    k_tw<<<32, 256, 0, stream>>>(wih0, tw0, 128);
    k_tw<<<16, 256, 0, stream>>>(whh0, tu0, 64);
    k_tw<<<16, 256, 0, stream>>>(wih1, tw1, 64);
    k_tw<<<16, 256, 0, stream>>>(whh1, tu1, 64);
    k_tw<<<16, 256, 0, stream>>>(wih2, tw2, 64);
    k_tw<<<16, 256, 0, stream>>>(whh2, tu2, 64);

    k_s2s4<<<KB, 256, 0, stream>>>(buf1, gstart,
        tw0, tu0, bih0, bhh0,
        tw1, tu1, bih1, bhh1,
        tw2, tu2, bih2, bhh2,
        gn_g, gn_b, fc1_w, fc1_b, bn_g, bn_b, bn_m, bn_v, fc2_w, fc2_b,
        out, flag);

    k_post<<<outBlocks, 256, 0, stream>>>(flag, out);
}

// Round 15
// 478.963 us; speedup vs baseline: 1.1927x; 1.0791x over previous
//
#include <hip/hip_runtime.h>

#define KN 32768
#define KE 65536
#define KB 512
#define KEPB 64
#define KNREG 33
#define KEORD (KE + KNREG * KEPB)   /* 67648 padded sorted-edge slots */
#define KNBLK (KEORD / KEPB)        /* 1057 edge blocks */

/* ---------------- workspace element offsets ---------------- */
/* zero-init zone */
#define O_BUF0 ((size_t)0)
#define O_BUF1 (O_BUF0 + (size_t)KN * 64)
#define O_DEG  (O_BUF1 + (size_t)KN * 64)
#define O_GCNT (O_DEG + KN)
#define O_GST  (O_GCNT + KB)
#define O_HIST (O_GST + KB + 8)          /* [2][64] */
#define O_CUR  (O_HIST + 128)            /* [2][64] */
#define O_FLAG (O_CUR + 128)
#define O_ZEND (O_FLAG + 64)
/* -1-init zone */
#define O_EORD ((O_ZEND + 63) & ~(size_t)63)    /* [2][KEORD] */
#define O_RBLK (O_EORD + 2 * (size_t)KEORD)     /* [2][1088] */
#define O_FEND (O_RBLK + 2 * 1088)
/* no-init zone (fully written before read) */
#define O_WB   ((O_FEND + 63) & ~(size_t)63)    /* [33][4096] */
#define O_WS   (O_WB + (size_t)KNREG * 4096)
#define O_CROSS (O_WS + (size_t)KNREG * 4096)   /* [32] */
#define O_RCNT (O_CROSS + 64)
#define O_AOFF (O_RCNT + 64)                     /* [2][64] */
#define O_REGN (O_AOFF + 128)                    /* [E] */
#define O_END  (O_REGN + KE)

__device__ float sigf(float x) { return 1.0f / (1.0f + expf(-x)); }

/* diagnostic fill (f32 output) */
extern "C" __global__ void GNNModule_9259949490279_kernel(float* out, float v) {
    int i = blockIdx.x * 256 + threadIdx.x;
    if (i < KB * 64) out[i] = v;
}

extern "C" __global__ void k_post(const int* flag, float* out) {
    int f = flag[0];
    if (f == 0) return;
    int i = blockIdx.x * 256 + threadIdx.x;
    if (i < KB * 64) out[i] = 300.0f + (float)f;
}

/* merged: zero-zone + (-1)-zone init in one launch */
extern "C" __global__ void k_init(float* wsf, int* wsi) {
    size_t i = (size_t)blockIdx.x * 256 + threadIdx.x;
    size_t stride = (size_t)gridDim.x * 256;
    for (size_t p = i; p < O_ZEND; p += stride) wsf[p] = 0.0f;
    for (size_t p = O_EORD + i; p < O_FEND; p += stride) wsi[p] = -1;
}

extern "C" __global__ void k_deg(const int* dst, float* deg, int* flag) {
    int e = blockIdx.x * 256 + threadIdx.x;
    if (e >= KE) return;
    int d = dst[e];
    if ((unsigned)d >= (unsigned)KN) { atomicOr(flag, 1); d = 0; }
    atomicAdd(&deg[d], 1.0f);
}

/* gid is SORTED -> a 256-node block spans few graphs; LDS histogram */
extern "C" __global__ void k_gcount(const int* gid, int* gcnt, int* flag) {
    __shared__ int lh[257];
    __shared__ int gminS;
    int t = threadIdx.x;
    int n = blockIdx.x * 256 + t;
    lh[t] = 0;
    if (t == 0) { lh[256] = 0; gminS = gid[blockIdx.x * 256]; }
    __syncthreads();
    int g = gid[n];
    if ((unsigned)g >= (unsigned)KB) { atomicOr(flag, 2); g = 0; }
    int gm = gminS;
    if ((unsigned)gm >= (unsigned)KB) gm = 0;
    int d = g - gm;
    if (d >= 0 && d < 257) atomicAdd(&lh[d], 1);
    else atomicAdd(&gcnt[g], 1);
    __syncthreads();
    if (lh[t] > 0) atomicAdd(&gcnt[gm + t], lh[t]);
    if (t == 0 && lh[256] > 0) atomicAdd(&gcnt[gm + 256], lh[256]);
}

extern "C" __global__ void k_gscan(const int* gcnt, int* gstart) {
    __shared__ int part[64];
    __shared__ int pre[64];
    int t = threadIdx.x;
    int v[8];
    int s = 0;
    int base = t * 8;
    for (int j = 0; j < 8; ++j) { v[j] = gcnt[base + j]; s += v[j]; }
    part[t] = s;
    __syncthreads();
    if (t == 0) {
        int run = 0;
        for (int i = 0; i < 64; ++i) { pre[i] = run; run += part[i]; }
    }
    __syncthreads();
    int run = pre[t];
    for (int j = 0; j < 8; ++j) { gstart[base + j] = run; run += v[j]; }
    if (t == 63) gstart[KB] = run;
}

/* ---- region machinery: exact piecewise-linear edge MLP ---- */
extern "C" __global__ void k_prep(const float* ew1, const float* eb1,
                                  float* cross, int* rcnt) {
    if (threadIdx.x != 0 || blockIdx.x != 0) return;
    float cl[32];
    int n = 0;
    for (int k = 0; k < 32; ++k) {
        float a = ew1[k], b = eb1[k];
        if (a != 0.0f) {
            float tt = -b / a;
            if (tt > 0.0f && tt < 1.0f) cl[n++] = tt;
        }
    }
    for (int i = 1; i < n; ++i) {
        float v = cl[i];
        int j = i - 1;
        while (j >= 0 && cl[j] > v) { cl[j + 1] = cl[j]; --j; }
        cl[j + 1] = v;
    }
    for (int i = 0; i < n; ++i) cross[i] = cl[i];
    *rcnt = n;
}

extern "C" __global__ __launch_bounds__(256) void k_mats(
    const float* ew1, const float* eb1, const float* ew2, const float* eb2,
    const float* cross, const int* rcnt, float* Wb, float* Ws) {
    int r = blockIdx.x;
    int n = *rcnt;
    if (r > n) return;
    float lo = (r == 0) ? 0.0f : cross[r - 1];
    float hi = (r == n) ? 1.0f : cross[r];
    float mid = 0.5f * (lo + hi);
    __shared__ float mw[32], mb[32];
    int t = threadIdx.x;
    if (t < 32) {
        bool act = (mid * ew1[t] + eb1[t]) > 0.0f;
        mw[t] = act ? ew1[t] : 0.0f;
        mb[t] = act ? eb1[t] : 0.0f;
    }
    __syncthreads();
    #pragma unroll
    for (int j = 0; j < 16; ++j) {
        int idx = j * 256 + t;
        float as = 0.0f, ab = eb2[idx];
        #pragma unroll
        for (int k4 = 0; k4 < 8; ++k4) {
            float4 w2 = *(const float4*)&ew2[(size_t)idx * 32 + 4 * k4];
            as += mw[4*k4+0]*w2.x + mw[4*k4+1]*w2.y + mw[4*k4+2]*w2.z + mw[4*k4+3]*w2.w;
            ab += mb[4*k4+0]*w2.x + mb[4*k4+1]*w2.y + mb[4*k4+2]*w2.z + mb[4*k4+3]*w2.w;
        }
        Wb[(size_t)r * 4096 + idx] = ab;
        Ws[(size_t)r * 4096 + idx] = as;
    }
}

/* LDS histogram -> <=33 global atomics per block */
extern "C" __global__ void k_region(const float* ef, const float* cross,
                                    const int* rcnt, int* region, int* hist) {
    __shared__ float lcross[32];
    __shared__ int lh[64];
    __shared__ int ln;
    int t = threadIdx.x;
    if (t == 0) ln = *rcnt;
    if (t < 64) lh[t] = 0;
    if (t >= 32 && t < 64) lcross[t - 32] = 0.0f;
    __syncthreads();
    if (t < 32 && t < ln) lcross[t] = cross[t];
    __syncthreads();
    int e = blockIdx.x * 256 + t;
    float f = ef[e];
    int n = ln, r = 0;
    for (int j = 0; j < n; ++j) r += (f > lcross[j]) ? 1 : 0;
    region[e] = r;
    atomicAdd(&lh[r], 1);
    __syncthreads();
    if (t < 64 && lh[t] > 0) atomicAdd(&hist[t], lh[t]);
}

extern "C" __global__ void k_scan(const int* hist, const int* rcnt,
                                  int* aoff, int* rblk) {
    if (threadIdx.x != 0 || blockIdx.x != 0) return;
    int R = *rcnt + 1;
    int base = 0;
    for (int r = 0; r < R; ++r) {
        aoff[r] = base * KEPB;
        int nb = (hist[r] + KEPB - 1) / KEPB;
        for (int j = 0; j < nb; ++j) rblk[base + j] = r;
        base += nb;
    }
}

/* local LDS rank + one chunk-reserving global atomic per (block,region) */
extern "C" __global__ void k_scatidx(const int* region, const int* aoff,
                                     int* cursor, int* eorder) {
    __shared__ int lcnt[64];
    __shared__ int lbase[64];
    int t = threadIdx.x;
    if (t < 64) lcnt[t] = 0;
    __syncthreads();
    int e = blockIdx.x * 256 + t;
    int r = region[e];
    int lr = atomicAdd(&lcnt[r], 1);
    __syncthreads();
    if (t < 64 && lcnt[t] > 0) lbase[t] = atomicAdd(&cursor[t], lcnt[t]);
    __syncthreads();
    eorder[aoff[r] + lbase[r] + lr] = e;
}

/* ---- edge message + scatter (HW-verified round 9, kept verbatim) ---- */
extern "C" __global__ __launch_bounds__(256) void k_edge(
    const float* x, const float* efeat, const int* src, const int* dst,
    const float* Wb, const float* Ws, const int* rblk, const int* eorder,
    float* sbuf) {
    __shared__ __align__(16) float mbuf[4096];
    __shared__ __align__(16) float msuf[4096];
    __shared__ __align__(16) float xs[4][16][64];
    int b = blockIdx.x;
    int r = rblk[b];
    if (r < 0) return;
    int t = threadIdx.x;
    const float4* gb = (const float4*)(Wb + (size_t)r * 4096);
    const float4* gs = (const float4*)(Ws + (size_t)r * 4096);
    float4* lb = (float4*)mbuf;
    float4* ls = (float4*)msuf;
    #pragma unroll
    for (int j = 0; j < 4; ++j) {
        lb[t + 256 * j] = gb[t + 256 * j];
        ls[t + 256 * j] = gs[t + 256 * j];
    }
    __syncthreads();
    int w = t >> 6, lane = t & 63;
    int base = b * KEPB + w * 16;
    int eid = (lane < 16) ? eorder[base + lane] : -1;
    float efl = 0.0f;
    int srl = 0, dsl = 0;
    if (eid >= 0) { efl = efeat[eid]; srl = src[eid]; dsl = dst[eid]; }
    unsigned long long vm = __ballot(eid >= 0);
    if ((vm & 0xFFFFull) == 0ull) return;
    float ef[16];
    int dv[16];
    #pragma unroll
    for (int s = 0; s < 16; ++s) {
        ef[s] = __shfl(efl, s);
        int sv = __shfl(srl, s);
        dv[s] = __shfl(dsl, s);
        xs[w][s][lane] = x[(size_t)sv * 64 + lane];
    }
    float acc[16];
    #pragma unroll
    for (int s = 0; s < 16; ++s) acc[s] = 0.0f;
    #pragma unroll 1
    for (int i4 = 0; i4 < 16; ++i4) {
        float wb0 = mbuf[(i4 * 4 + 0) * 64 + lane], ws0 = msuf[(i4 * 4 + 0) * 64 + lane];
        float wb1 = mbuf[(i4 * 4 + 1) * 64 + lane], ws1 = msuf[(i4 * 4 + 1) * 64 + lane];
        float wb2 = mbuf[(i4 * 4 + 2) * 64 + lane], ws2 = msuf[(i4 * 4 + 2) * 64 + lane];
        float wb3 = mbuf[(i4 * 4 + 3) * 64 + lane], ws3 = msuf[(i4 * 4 + 3) * 64 + lane];
        #pragma unroll
        for (int j = 0; j < 16; ++j) {
            float4 xv = *(const float4*)&xs[w][j][i4 * 4];
            acc[j] = fmaf(xv.x, fmaf(ef[j], ws0, wb0), acc[j]);
            acc[j] = fmaf(xv.y, fmaf(ef[j], ws1, wb1), acc[j]);
            acc[j] = fmaf(xv.z, fmaf(ef[j], ws2, wb2), acc[j]);
            acc[j] = fmaf(xv.w, fmaf(ef[j], ws3, wb3), acc[j]);
        }
    }
    #pragma unroll
    for (int j = 0; j < 16; ++j) {
        if ((vm >> j) & 1ull) atomicAdd(&sbuf[(size_t)dv[j] * 64 + lane], acc[j]);
    }
}

extern "C" __global__ void k_final0(float* s, const float* deg, const float* cb, int* flag) {
    int idx = blockIdx.x * 256 + threadIdx.x;
    int n = idx >> 6;
    int o = idx & 63;
    float d = deg[n];
    if (d < 1.0f) d = 1.0f;
    float v = s[idx] / d + cb[o];
    if (v < 0.0f) v = 0.0f;
    if (!(v == v)) { v = 0.0f; atomicOr(flag, 32); }
    s[idx] = v;
}

extern "C" __global__ void k_final1ln(float* s, const float* deg, const float* cb,
                                      const float* lg, const float* lb, int* flag) {
    __shared__ float red[64];
    int t = threadIdx.x;
    int n = blockIdx.x;
    float d = deg[n];
    if (d < 1.0f) d = 1.0f;
    float v = s[(size_t)n * 64 + t] / d + cb[t];
    if (v < 0.0f) v = 0.0f;
    red[t] = v;
    __syncthreads();
    for (int m = 32; m >= 1; m >>= 1) {
        if (t < m) red[t] += red[t + m];
        __syncthreads();
    }
    float mu = red[0] * (1.0f / 64.0f);
    __syncthreads();
    red[t] = v * v;
    __syncthreads();
    for (int m = 32; m >= 1; m >>= 1) {
        if (t < m) red[t] += red[t + m];
        __syncthreads();
    }
    float var = red[0] * (1.0f / 64.0f) - mu * mu;
    float rs = rsqrtf(var + 1e-5f);
    float r = (v - mu) * rs * lg[t] + lb[t];
    if (!(r == r)) { r = 0.0f; atomicOr(flag, 8); }
    s[(size_t)n * 64 + t] = r;
}

/* ---- Set2Set + head v5: round-11 LSTM body (row-gather weights, 88 VGPR)
   + x-slab staged in LDS ONCE (cnt<=192; global fallback otherwise)
   + wave-shfl attention reductions (fewer barriers) ---- */
extern "C" __global__ __launch_bounds__(256) void k_s2s5(
    const float* x, const int* gstart,
    const float* wih0, const float* whh0, const float* bih0, const float* bhh0,
    const float* wih1, const float* whh1, const float* bih1, const float* bhh1,
    const float* wih2, const float* whh2, const float* bih2, const float* bhh2,
    const float* gn_g, const float* gn_b,
    const float* fc1_w, const float* fc1_b,
    const float* bn_g, const float* bn_b, const float* bn_m, const float* bn_v,
    const float* fc2_w, const float* fc2_b,
    float* out, int* flag) {
    __shared__ __align__(16) float xls[192 * 64];   /* 48 KB x-slab */
    __shared__ __align__(16) float esc[1024];
    __shared__ __align__(16) float qs[128];
    __shared__ __align__(16) float hs0[64];
    __shared__ __align__(16) float hs1[64];
    __shared__ __align__(16) float hs2[64];
    __shared__ __align__(16) float cs[3][64];
    __shared__ __align__(16) float gat[256];
    __shared__ __align__(16) float red4[4][64];
    __shared__ float mzz[4], zzz[4];
    int t = threadIdx.x;           /* 0..255 */
    int g = blockIdx.x;
    int w = t >> 6, lane = t & 63;

    int n0 = gstart[g];
    int n1 = gstart[g + 1];
    if (n0 < 0) n0 = 0;
    if (n0 > KN) n0 = KN;
    if (n1 < n0) n1 = n0;
    if (n1 > KN) n1 = KN;
    int cnt = n1 - n0;
    if (cnt > 1024) { cnt = 1024; if (t == 0) atomicOr(flag, 16); }
    int useLds = (cnt <= 192);

    if (useLds) {
        int tot = cnt * 64;
        for (int u = t; u < tot; u += 256) xls[u] = x[(size_t)n0 * 64 + u];
    }
    if (t < 128) qs[t] = 0.0f;
    if (t < 64) {
        hs0[t] = 0.0f; hs1[t] = 0.0f; hs2[t] = 0.0f;
        cs[0][t] = 0.0f; cs[1][t] = 0.0f; cs[2][t] = 0.0f;
    }
    __syncthreads();

    for (int it = 0; it < 6; ++it) {
        /* layer 0: K=128, input qs (row-gather weights, round-11 form) */
        {
            float a = bih0[t] + bhh0[t];
            const float4* wr = (const float4*)(wih0 + (size_t)t * 128);
            const float4* q4 = (const float4*)qs;
            #pragma unroll
            for (int k4 = 0; k4 < 32; ++k4) {
                float4 wv = wr[k4];
                float4 xv = q4[k4];
                a += wv.x*xv.x + wv.y*xv.y + wv.z*xv.z + wv.w*xv.w;
            }
            const float4* ur = (const float4*)(whh0 + (size_t)t * 64);
            const float4* h4 = (const float4*)hs0;
            #pragma unroll
            for (int k4 = 0; k4 < 16; ++k4) {
                float4 wv = ur[k4];
                float4 hv = h4[k4];
                a += wv.x*hv.x + wv.y*hv.y + wv.z*hv.z + wv.w*hv.w;
            }
            gat[t] = a;
            __syncthreads();
            if (t < 64) {
                float c = sigf(gat[64 + t]) * cs[0][t] + sigf(gat[t]) * tanhf(gat[128 + t]);
                cs[0][t] = c;
                hs0[t] = sigf(gat[192 + t]) * tanhf(c);
            }
            __syncthreads();
        }
        /* layer 1 */
        {
            float a = bih1[t] + bhh1[t];
            const float4* wr = (const float4*)(wih1 + (size_t)t * 64);
            const float4* ur = (const float4*)(whh1 + (size_t)t * 64);
            const float4* i4 = (const float4*)hs0;
            const float4* h4 = (const float4*)hs1;
            #pragma unroll
            for (int k4 = 0; k4 < 16; ++k4) {
                float4 wv = wr[k4];
                float4 xv = i4[k4];
                a += wv.x*xv.x + wv.y*xv.y + wv.z*xv.z + wv.w*xv.w;
                float4 uv = ur[k4];
                float4 hv = h4[k4];
                a += uv.x*hv.x + uv.y*hv.y + uv.z*hv.z + uv.w*hv.w;
            }
            gat[t] = a;
            __syncthreads();
            if (t < 64) {
                float c = sigf(gat[64 + t]) * cs[1][t] + sigf(gat[t]) * tanhf(gat[128 + t]);
                cs[1][t] = c;
                hs1[t] = sigf(gat[192 + t]) * tanhf(c);
            }
            __syncthreads();
        }
        /* layer 2 */
        {
            float a = bih2[t] + bhh2[t];
            const float4* wr = (const float4*)(wih2 + (size_t)t * 64);
            const float4* ur = (const float4*)(whh2 + (size_t)t * 64);
            const float4* i4 = (const float4*)hs1;
            const float4* h4 = (const float4*)hs2;
            #pragma unroll
            for (int k4 = 0; k4 < 16; ++k4) {
                float4 wv = wr[k4];
                float4 xv = i4[k4];
                a += wv.x*xv.x + wv.y*xv.y + wv.z*xv.z + wv.w*xv.w;
                float4 uv = ur[k4];
                float4 hv = h4[k4];
                a += uv.x*hv.x + uv.y*hv.y + uv.z*hv.z + uv.w*hv.w;
            }
            gat[t] = a;
            __syncthreads();
            if (t < 64) {
                float c = sigf(gat[64 + t]) * cs[2][t] + sigf(gat[t]) * tanhf(gat[128 + t]);
                cs[2][t] = c;
                hs2[t] = sigf(gat[192 + t]) * tanhf(c);
            }
            __syncthreads();
        }
        /* attention: wave-cooperative rows from LDS (or global fallback) */
        {
            float q = hs2[lane];
            float mx = -3.0e38f;
            for (int p = w; p < cnt; p += 4) {
                float xv = useLds ? xls[p * 64 + lane]
                                  : x[(size_t)(n0 + p) * 64 + lane];
                float v = xv * q;
                v += __shfl_xor(v, 1);
                v += __shfl_xor(v, 2);
                v += __shfl_xor(v, 4);
                v += __shfl_xor(v, 8);
                v += __shfl_xor(v, 16);
                v += __shfl_xor(v, 32);
                if (lane == 0) esc[p] = v;
                if (v > mx) mx = v;
            }
            if (lane == 0) mzz[w] = mx;
            __syncthreads();
            float M = mzz[0];
            if (mzz[1] > M) M = mzz[1];
            if (mzz[2] > M) M = mzz[2];
            if (mzz[3] > M) M = mzz[3];
            float z = 0.0f;
            for (int p = t; p < cnt; p += 256) {
                float e = expf(esc[p] - M);
                esc[p] = e;
                z += e;
            }
            z += __shfl_xor(z, 1);
            z += __shfl_xor(z, 2);
            z += __shfl_xor(z, 4);
            z += __shfl_xor(z, 8);
            z += __shfl_xor(z, 16);
            z += __shfl_xor(z, 32);
            if (lane == 0) zzz[w] = z;
            __syncthreads();
            float Z = zzz[0] + zzz[1] + zzz[2] + zzz[3];
            float rd = 0.0f;
            for (int p = w; p < cnt; p += 4) {
                float xv = useLds ? xls[p * 64 + lane]
                                  : x[(size_t)(n0 + p) * 64 + lane];
                rd += xv * esc[p];
            }
            red4[w][lane] = rd;
            __syncthreads();
            if (t < 64) {
                float r = red4[0][t] + red4[1][t] + red4[2][t] + red4[3][t];
                r = (cnt > 0 && Z > 0.0f) ? r / Z : 0.0f;
                qs[t] = hs2[t];
                qs[64 + t] = r;
            }
            __syncthreads();
        }
    }

    /* head: graphnorm -> fc1 -> bn -> relu -> fc2 -> relu */
    float v = (t < 128) ? qs[t] : 0.0f;
    gat[t] = v;
    __syncthreads();
    for (int m = 128; m >= 1; m >>= 1) {
        if (t < m) gat[t] += gat[t + m];
        __syncthreads();
    }
    float mu = gat[0] * (1.0f / 128.0f);
    __syncthreads();
    gat[t] = v * v;
    __syncthreads();
    for (int m = 128; m >= 1; m >>= 1) {
        if (t < m) gat[t] += gat[t + m];
        __syncthreads();
    }
    float var = gat[0] * (1.0f / 128.0f) - mu * mu;
    float rs = rsqrtf(var + 1e-5f);
    if (t < 128) esc[t] = (v - mu) * rs * gn_g[t] + gn_b[t];
    __syncthreads();
    if (t < 128) {
        float y = fc1_b[t];
        const float4* wr = (const float4*)(fc1_w + (size_t)t * 128);
        #pragma unroll
        for (int k4 = 0; k4 < 32; ++k4) {
            float4 wv = wr[k4];
            float4 gv = *(const float4*)&esc[4 * k4];
            y += wv.x*gv.x + wv.y*gv.y + wv.z*gv.z + wv.w*gv.w;
        }
        y = (y - bn_m[t]) * rsqrtf(bn_v[t] + 1e-5f) * bn_g[t] + bn_b[t];
        if (y < 0.0f) y = 0.0f;
        gat[t] = y;
    }
    __syncthreads();
    if (t < 64) {
        float o = fc2_b[t];
        const float4* wr = (const float4*)(fc2_w + (size_t)t * 128);
        #pragma unroll
        for (int k4 = 0; k4 < 32; ++k4) {
            float4 wv = wr[k4];
            float4 yv = *(const float4*)&gat[4 * k4];
            o += wv.x*yv.x + wv.y*yv.y + wv.z*yv.z + wv.w*yv.w;
        }
        if (!(o == o)) o = 999.0f;
        else if (o < 0.0f) o = 0.0f;
        out[(size_t)g * 64 + t] = o;
    }
}

extern "C" void kernel_launch(void* const* d_in, const int* in_sizes, int n_in,
                              void* d_out, int out_size, void* d_ws, size_t ws_size,
                              hipStream_t stream) {
    float* out = (float*)d_out;
    const int outBlocks = (KB * 64 + 255) / 256;

    if (n_in != 39) {
        GNNModule_9259949490279_kernel<<<outBlocks, 256, 0, stream>>>(out, 50.0f);
        return;
    }
    if (in_sizes[0] != KN * 64 || in_sizes[1] != KE || in_sizes[4] != KN) {
        GNNModule_9259949490279_kernel<<<outBlocks, 256, 0, stream>>>(out, 60.0f);
        return;
    }
    if (out_size != KB * 64) {
        GNNModule_9259949490279_kernel<<<outBlocks, 256, 0, stream>>>(out, 80.0f);
        return;
    }
    if (ws_size < O_END * 4) {
        GNNModule_9259949490279_kernel<<<outBlocks, 256, 0, stream>>>(out, 100.0f);
        return;
    }

    const float* atom = (const float*)d_in[0];
    const float* efeat = (const float*)d_in[1];
    const int* src = (const int*)d_in[2];
    const int* dst = (const int*)d_in[3];
    const int* gid = (const int*)d_in[4];
    const float* ew1[2] = {(const float*)d_in[5], (const float*)d_in[10]};
    const float* eb1[2] = {(const float*)d_in[6], (const float*)d_in[11]};
    const float* ew2[2] = {(const float*)d_in[7], (const float*)d_in[12]};
    const float* eb2[2] = {(const float*)d_in[8], (const float*)d_in[13]};
    const float* cb[2] = {(const float*)d_in[9], (const float*)d_in[14]};
    const float* ln_g = (const float*)d_in[15];
    const float* ln_b = (const float*)d_in[16];
    const float* wih0 = (const float*)d_in[17];
    const float* whh0 = (const float*)d_in[18];
    const float* bih0 = (const float*)d_in[19];
    const float* bhh0 = (const float*)d_in[20];
    const float* wih1 = (const float*)d_in[21];
    const float* whh1 = (const float*)d_in[22];
    const float* bih1 = (const float*)d_in[23];
    const float* bhh1 = (const float*)d_in[24];
    const float* wih2 = (const float*)d_in[25];
    const float* whh2 = (const float*)d_in[26];
    const float* bih2 = (const float*)d_in[27];
    const float* bhh2 = (const float*)d_in[28];
    const float* gn_g = (const float*)d_in[29];
    const float* gn_b = (const float*)d_in[30];
    const float* fc1_w = (const float*)d_in[31];
    const float* fc1_b = (const float*)d_in[32];
    const float* bn_g = (const float*)d_in[33];
    const float* bn_b = (const float*)d_in[34];
    const float* bn_m = (const float*)d_in[35];
    const float* bn_v = (const float*)d_in[36];
    const float* fc2_w = (const float*)d_in[37];
    const float* fc2_b = (const float*)d_in[38];

    float* wsf = (float*)d_ws;
    int* wsi = (int*)d_ws;
    float* buf0 = wsf + O_BUF0;
    float* buf1 = wsf + O_BUF1;
    float* deg = wsf + O_DEG;
    int* gcnt = wsi + O_GCNT;
    int* gstart = wsi + O_GST;
    int* flag = wsi + O_FLAG;
    float* Wb = wsf + O_WB;
    float* Ws = wsf + O_WS;
    float* cross = wsf + O_CROSS;
    int* rcnt = wsi + O_RCNT;
    int* region = wsi + O_REGN;

    k_init<<<2048, 256, 0, stream>>>(wsf, wsi);

    k_deg<<<KE / 256, 256, 0, stream>>>(dst, deg, flag);
    k_gcount<<<KN / 256, 256, 0, stream>>>(gid, gcnt, flag);
    k_gscan<<<1, 64, 0, stream>>>(gcnt, gstart);

    for (int l = 0; l < 2; ++l) {
        const float* xin = (l == 0) ? atom : buf0;
        float* sout = (l == 0) ? buf0 : buf1;
        int* hist = wsi + O_HIST + l * 64;
        int* cursor = wsi + O_CUR + l * 64;
        int* aoff = wsi + O_AOFF + l * 64;
        int* eorder = wsi + O_EORD + l * KEORD;
        int* rblk = wsi + O_RBLK + l * 1088;

        k_prep<<<1, 64, 0, stream>>>(ew1[l], eb1[l], cross, rcnt);
        k_mats<<<KNREG, 256, 0, stream>>>(ew1[l], eb1[l], ew2[l], eb2[l], cross, rcnt, Wb, Ws);
        k_region<<<KE / 256, 256, 0, stream>>>(efeat, cross, rcnt, region, hist);
        k_scan<<<1, 64, 0, stream>>>(hist, rcnt, aoff, rblk);
        k_scatidx<<<KE / 256, 256, 0, stream>>>(region, aoff, cursor, eorder);
        k_edge<<<KNBLK, 256, 0, stream>>>(xin, efeat, src, dst, Wb, Ws, rblk, eorder, sout);
        if (l == 0) {
            k_final0<<<KN * 64 / 256, 256, 0, stream>>>(buf0, deg, cb[0], flag);
        } else {
            k_final1ln<<<KN, 64, 0, stream>>>(buf1, deg, cb[1], ln_g, ln_b, flag);
        }
    }

    k_s2s5<<<KB, 256, 0, stream>>>(buf1, gstart,
        wih0, whh0, bih0, bhh0,
        wih1, whh1, bih1, bhh1,
        wih2, whh2, bih2, bhh2,
        gn_g, gn_b, fc1_w, fc1_b, bn_g, bn_b, bn_m, bn_v, fc2_w, fc2_b,
        out, flag);

    k_post<<<outBlocks, 256, 0, stream>>>(flag, out);
}

// Round 16
// 464.830 us; speedup vs baseline: 1.2289x; 1.0304x over previous
//
#include <hip/hip_runtime.h>

#define KN 32768
#define KE 65536
#define KB 512
#define KEPB 64
#define KNREG 33
#define KEORD (KE + KNREG * KEPB)   /* 67648 padded sorted-edge slots */
#define KNBLK (KEORD / KEPB)        /* 1057 edge blocks */

/* ---------------- workspace element offsets ---------------- */
/* zero-init zone */
#define O_BUF0 ((size_t)0)
#define O_BUF1 (O_BUF0 + (size_t)KN * 64)
#define O_DEG  (O_BUF1 + (size_t)KN * 64)
#define O_GCNT (O_DEG + KN)
#define O_GST  (O_GCNT + KB)
#define O_HIST (O_GST + KB + 8)          /* [2][64] */
#define O_CUR  (O_HIST + 128)            /* [2][64] */
#define O_FLAG (O_CUR + 128)
#define O_ZEND (O_FLAG + 64)
/* -1-init zone */
#define O_EORD ((O_ZEND + 63) & ~(size_t)63)    /* [2][KEORD] */
#define O_RBLK (O_EORD + 2 * (size_t)KEORD)     /* [2][1088] */
#define O_FEND (O_RBLK + 2 * 1088)
/* no-init zone (fully written before read) */
#define O_WB   ((O_FEND + 63) & ~(size_t)63)    /* [33][4096] */
#define O_WS   (O_WB + (size_t)KNREG * 4096)
#define O_CROSS (O_WS + (size_t)KNREG * 4096)   /* [32] */
#define O_RCNT (O_CROSS + 64)
#define O_AOFF (O_RCNT + 64)                     /* [2][64] */
#define O_REGN (O_AOFF + 128)                    /* [E] */
#define O_END  (O_REGN + KE)

__device__ float sigf(float x) { return 1.0f / (1.0f + expf(-x)); }

/* diagnostic fill (f32 output) */
extern "C" __global__ void GNNModule_9259949490279_kernel(float* out, float v) {
    int i = blockIdx.x * 256 + threadIdx.x;
    if (i < KB * 64) out[i] = v;
}

extern "C" __global__ void k_post(const int* flag, float* out) {
    int f = flag[0];
    if (f == 0) return;
    int i = blockIdx.x * 256 + threadIdx.x;
    if (i < KB * 64) out[i] = 300.0f + (float)f;
}

/* merged: zero-zone + (-1)-zone init in one launch */
extern "C" __global__ void k_init(float* wsf, int* wsi) {
    size_t i = (size_t)blockIdx.x * 256 + threadIdx.x;
    size_t stride = (size_t)gridDim.x * 256;
    for (size_t p = i; p < O_ZEND; p += stride) wsf[p] = 0.0f;
    for (size_t p = O_EORD + i; p < O_FEND; p += stride) wsi[p] = -1;
}

extern "C" __global__ void k_deg(const int* dst, float* deg, int* flag) {
    int e = blockIdx.x * 256 + threadIdx.x;
    if (e >= KE) return;
    int d = dst[e];
    if ((unsigned)d >= (unsigned)KN) { atomicOr(flag, 1); d = 0; }
    atomicAdd(&deg[d], 1.0f);
}

/* gid is SORTED -> a 256-node block spans few graphs; LDS histogram */
extern "C" __global__ void k_gcount(const int* gid, int* gcnt, int* flag) {
    __shared__ int lh[257];
    __shared__ int gminS;
    int t = threadIdx.x;
    int n = blockIdx.x * 256 + t;
    lh[t] = 0;
    if (t == 0) { lh[256] = 0; gminS = gid[blockIdx.x * 256]; }
    __syncthreads();
    int g = gid[n];
    if ((unsigned)g >= (unsigned)KB) { atomicOr(flag, 2); g = 0; }
    int gm = gminS;
    if ((unsigned)gm >= (unsigned)KB) gm = 0;
    int d = g - gm;
    if (d >= 0 && d < 257) atomicAdd(&lh[d], 1);
    else atomicAdd(&gcnt[g], 1);
    __syncthreads();
    if (lh[t] > 0) atomicAdd(&gcnt[gm + t], lh[t]);
    if (t == 0 && lh[256] > 0) atomicAdd(&gcnt[gm + 256], lh[256]);
}

extern "C" __global__ void k_gscan(const int* gcnt, int* gstart) {
    __shared__ int part[64];
    __shared__ int pre[64];
    int t = threadIdx.x;
    int v[8];
    int s = 0;
    int base = t * 8;
    for (int j = 0; j < 8; ++j) { v[j] = gcnt[base + j]; s += v[j]; }
    part[t] = s;
    __syncthreads();
    if (t == 0) {
        int run = 0;
        for (int i = 0; i < 64; ++i) { pre[i] = run; run += part[i]; }
    }
    __syncthreads();
    int run = pre[t];
    for (int j = 0; j < 8; ++j) { gstart[base + j] = run; run += v[j]; }
    if (t == 63) gstart[KB] = run;
}

/* ---- region machinery: exact piecewise-linear edge MLP ---- */
extern "C" __global__ void k_prep(const float* ew1, const float* eb1,
                                  float* cross, int* rcnt) {
    if (threadIdx.x != 0 || blockIdx.x != 0) return;
    float cl[32];
    int n = 0;
    for (int k = 0; k < 32; ++k) {
        float a = ew1[k], b = eb1[k];
        if (a != 0.0f) {
            float tt = -b / a;
            if (tt > 0.0f && tt < 1.0f) cl[n++] = tt;
        }
    }
    for (int i = 1; i < n; ++i) {
        float v = cl[i];
        int j = i - 1;
        while (j >= 0 && cl[j] > v) { cl[j + 1] = cl[j]; --j; }
        cl[j + 1] = v;
    }
    for (int i = 0; i < n; ++i) cross[i] = cl[i];
    *rcnt = n;
}

extern "C" __global__ __launch_bounds__(256) void k_mats(
    const float* ew1, const float* eb1, const float* ew2, const float* eb2,
    const float* cross, const int* rcnt, float* Wb, float* Ws) {
    int r = blockIdx.x;
    int n = *rcnt;
    if (r > n) return;
    float lo = (r == 0) ? 0.0f : cross[r - 1];
    float hi = (r == n) ? 1.0f : cross[r];
    float mid = 0.5f * (lo + hi);
    __shared__ float mw[32], mb[32];
    int t = threadIdx.x;
    if (t < 32) {
        bool act = (mid * ew1[t] + eb1[t]) > 0.0f;
        mw[t] = act ? ew1[t] : 0.0f;
        mb[t] = act ? eb1[t] : 0.0f;
    }
    __syncthreads();
    #pragma unroll
    for (int j = 0; j < 16; ++j) {
        int idx = j * 256 + t;
        float as = 0.0f, ab = eb2[idx];
        #pragma unroll
        for (int k4 = 0; k4 < 8; ++k4) {
            float4 w2 = *(const float4*)&ew2[(size_t)idx * 32 + 4 * k4];
            as += mw[4*k4+0]*w2.x + mw[4*k4+1]*w2.y + mw[4*k4+2]*w2.z + mw[4*k4+3]*w2.w;
            ab += mb[4*k4+0]*w2.x + mb[4*k4+1]*w2.y + mb[4*k4+2]*w2.z + mb[4*k4+3]*w2.w;
        }
        Wb[(size_t)r * 4096 + idx] = ab;
        Ws[(size_t)r * 4096 + idx] = as;
    }
}

/* LDS histogram -> <=33 global atomics per block */
extern "C" __global__ void k_region(const float* ef, const float* cross,
                                    const int* rcnt, int* region, int* hist) {
    __shared__ float lcross[32];
    __shared__ int lh[64];
    __shared__ int ln;
    int t = threadIdx.x;
    if (t == 0) ln = *rcnt;
    if (t < 64) lh[t] = 0;
    if (t >= 32 && t < 64) lcross[t - 32] = 0.0f;
    __syncthreads();
    if (t < 32 && t < ln) lcross[t] = cross[t];
    __syncthreads();
    int e = blockIdx.x * 256 + t;
    float f = ef[e];
    int n = ln, r = 0;
    for (int j = 0; j < n; ++j) r += (f > lcross[j]) ? 1 : 0;
    region[e] = r;
    atomicAdd(&lh[r], 1);
    __syncthreads();
    if (t < 64 && lh[t] > 0) atomicAdd(&hist[t], lh[t]);
}

extern "C" __global__ void k_scan(const int* hist, const int* rcnt,
                                  int* aoff, int* rblk) {
    if (threadIdx.x != 0 || blockIdx.x != 0) return;
    int R = *rcnt + 1;
    int base = 0;
    for (int r = 0; r < R; ++r) {
        aoff[r] = base * KEPB;
        int nb = (hist[r] + KEPB - 1) / KEPB;
        for (int j = 0; j < nb; ++j) rblk[base + j] = r;
        base += nb;
    }
}

/* local LDS rank + one chunk-reserving global atomic per (block,region) */
extern "C" __global__ void k_scatidx(const int* region, const int* aoff,
                                     int* cursor, int* eorder) {
    __shared__ int lcnt[64];
    __shared__ int lbase[64];
    int t = threadIdx.x;
    if (t < 64) lcnt[t] = 0;
    __syncthreads();
    int e = blockIdx.x * 256 + t;
    int r = region[e];
    int lr = atomicAdd(&lcnt[r], 1);
    __syncthreads();
    if (t < 64 && lcnt[t] > 0) lbase[t] = atomicAdd(&cursor[t], lcnt[t]);
    __syncthreads();
    eorder[aoff[r] + lbase[r] + lr] = e;
}

/* ---- edge message + scatter (HW-verified round 9, kept verbatim) ---- */
extern "C" __global__ __launch_bounds__(256) void k_edge(
    const float* x, const float* efeat, const int* src, const int* dst,
    const float* Wb, const float* Ws, const int* rblk, const int* eorder,
    float* sbuf) {
    __shared__ __align__(16) float mbuf[4096];
    __shared__ __align__(16) float msuf[4096];
    __shared__ __align__(16) float xs[4][16][64];
    int b = blockIdx.x;
    int r = rblk[b];
    if (r < 0) return;
    int t = threadIdx.x;
    const float4* gb = (const float4*)(Wb + (size_t)r * 4096);
    const float4* gs = (const float4*)(Ws + (size_t)r * 4096);
    float4* lb = (float4*)mbuf;
    float4* ls = (float4*)msuf;
    #pragma unroll
    for (int j = 0; j < 4; ++j) {
        lb[t + 256 * j] = gb[t + 256 * j];
        ls[t + 256 * j] = gs[t + 256 * j];
    }
    __syncthreads();
    int w = t >> 6, lane = t & 63;
    int base = b * KEPB + w * 16;
    int eid = (lane < 16) ? eorder[base + lane] : -1;
    float efl = 0.0f;
    int srl = 0, dsl = 0;
    if (eid >= 0) { efl = efeat[eid]; srl = src[eid]; dsl = dst[eid]; }
    unsigned long long vm = __ballot(eid >= 0);
    if ((vm & 0xFFFFull) == 0ull) return;
    float ef[16];
    int dv[16];
    #pragma unroll
    for (int s = 0; s < 16; ++s) {
        ef[s] = __shfl(efl, s);
        int sv = __shfl(srl, s);
        dv[s] = __shfl(dsl, s);
        xs[w][s][lane] = x[(size_t)sv * 64 + lane];
    }
    float acc[16];
    #pragma unroll
    for (int s = 0; s < 16; ++s) acc[s] = 0.0f;
    #pragma unroll 1
    for (int i4 = 0; i4 < 16; ++i4) {
        float wb0 = mbuf[(i4 * 4 + 0) * 64 + lane], ws0 = msuf[(i4 * 4 + 0) * 64 + lane];
        float wb1 = mbuf[(i4 * 4 + 1) * 64 + lane], ws1 = msuf[(i4 * 4 + 1) * 64 + lane];
        float wb2 = mbuf[(i4 * 4 + 2) * 64 + lane], ws2 = msuf[(i4 * 4 + 2) * 64 + lane];
        float wb3 = mbuf[(i4 * 4 + 3) * 64 + lane], ws3 = msuf[(i4 * 4 + 3) * 64 + lane];
        #pragma unroll
        for (int j = 0; j < 16; ++j) {
            float4 xv = *(const float4*)&xs[w][j][i4 * 4];
            acc[j] = fmaf(xv.x, fmaf(ef[j], ws0, wb0), acc[j]);
            acc[j] = fmaf(xv.y, fmaf(ef[j], ws1, wb1), acc[j]);
            acc[j] = fmaf(xv.z, fmaf(ef[j], ws2, wb2), acc[j]);
            acc[j] = fmaf(xv.w, fmaf(ef[j], ws3, wb3), acc[j]);
        }
    }
    #pragma unroll
    for (int j = 0; j < 16; ++j) {
        if ((vm >> j) & 1ull) atomicAdd(&sbuf[(size_t)dv[j] * 64 + lane], acc[j]);
    }
}

extern "C" __global__ void k_final0(float* s, const float* deg, const float* cb, int* flag) {
    int idx = blockIdx.x * 256 + threadIdx.x;
    int n = idx >> 6;
    int o = idx & 63;
    float d = deg[n];
    if (d < 1.0f) d = 1.0f;
    float v = s[idx] / d + cb[o];
    if (v < 0.0f) v = 0.0f;
    if (!(v == v)) { v = 0.0f; atomicOr(flag, 32); }
    s[idx] = v;
}

extern "C" __global__ void k_final1ln(float* s, const float* deg, const float* cb,
                                      const float* lg, const float* lb, int* flag) {
    __shared__ float red[64];
    int t = threadIdx.x;
    int n = blockIdx.x;
    float d = deg[n];
    if (d < 1.0f) d = 1.0f;
    float v = s[(size_t)n * 64 + t] / d + cb[t];
    if (v < 0.0f) v = 0.0f;
    red[t] = v;
    __syncthreads();
    for (int m = 32; m >= 1; m >>= 1) {
        if (t < m) red[t] += red[t + m];
        __syncthreads();
    }
    float mu = red[0] * (1.0f / 64.0f);
    __syncthreads();
    red[t] = v * v;
    __syncthreads();
    for (int m = 32; m >= 1; m >>= 1) {
        if (t < m) red[t] += red[t + m];
        __syncthreads();
    }
    float var = red[0] * (1.0f / 64.0f) - mu * mu;
    float rs = rsqrtf(var + 1e-5f);
    float r = (v - mu) * rs * lg[t] + lb[t];
    if (!(r == r)) { r = 0.0f; atomicOr(flag, 8); }
    s[(size_t)n * 64 + t] = r;
}

/* ---- Set2Set + head v6: 512 blocks x 512 THREADS, k-split gate dot products
   (halved serial load chain, 2x wave count), 8-wave attention ---- */
extern "C" __global__ __launch_bounds__(512) void k_s2s6(
    const float* x, const int* gstart,
    const float* wih0, const float* whh0, const float* bih0, const float* bhh0,
    const float* wih1, const float* whh1, const float* bih1, const float* bhh1,
    const float* wih2, const float* whh2, const float* bih2, const float* bhh2,
    const float* gn_g, const float* gn_b,
    const float* fc1_w, const float* fc1_b,
    const float* bn_g, const float* bn_b, const float* bn_m, const float* bn_v,
    const float* fc2_w, const float* fc2_b,
    float* out, int* flag) {
    __shared__ __align__(16) float qs[128];
    __shared__ __align__(16) float hs0[64];
    __shared__ __align__(16) float hs1[64];
    __shared__ __align__(16) float hs2[64];
    __shared__ __align__(16) float cs[3][64];
    __shared__ __align__(16) float gatp[2][256];
    __shared__ __align__(16) float esc[1024];
    __shared__ __align__(16) float red8[8][64];
    __shared__ float mzz[8], zzz[8];
    int t = threadIdx.x;            /* 0..511 */
    int g = blockIdx.x;
    int r = t & 255, h = t >> 8;    /* gate row, k-half */
    int w = t >> 6, lane = t & 63;  /* wave 0..7 */

    if (t < 128) qs[t] = 0.0f;
    if (t < 64) {
        hs0[t] = 0.0f; hs1[t] = 0.0f; hs2[t] = 0.0f;
        cs[0][t] = 0.0f; cs[1][t] = 0.0f; cs[2][t] = 0.0f;
    }
    __syncthreads();

    int n0 = gstart[g];
    int n1 = gstart[g + 1];
    if (n0 < 0) n0 = 0;
    if (n0 > KN) n0 = KN;
    if (n1 < n0) n1 = n0;
    if (n1 > KN) n1 = KN;
    int cnt = n1 - n0;
    if (cnt > 1024) { cnt = 1024; if (t == 0) atomicOr(flag, 16); }

    for (int it = 0; it < 6; ++it) {
        /* layer 0: K=192 split in halves of 96 (qs 64 + hs0 32) */
        {
            float a = (h == 0) ? (bih0[r] + bhh0[r]) : 0.0f;
            const float4* wr = (const float4*)(wih0 + (size_t)r * 128) + h * 16;
            const float4* q4 = (const float4*)qs + h * 16;
            #pragma unroll
            for (int k4 = 0; k4 < 16; ++k4) {
                float4 wv = wr[k4];
                float4 xv = q4[k4];
                a += wv.x*xv.x + wv.y*xv.y + wv.z*xv.z + wv.w*xv.w;
            }
            const float4* ur = (const float4*)(whh0 + (size_t)r * 64) + h * 8;
            const float4* h4 = (const float4*)hs0 + h * 8;
            #pragma unroll
            for (int k4 = 0; k4 < 8; ++k4) {
                float4 wv = ur[k4];
                float4 hv = h4[k4];
                a += wv.x*hv.x + wv.y*hv.y + wv.z*hv.z + wv.w*hv.w;
            }
            gatp[h][r] = a;
            __syncthreads();
            if (t < 64) {
                float gi = gatp[0][t] + gatp[1][t];
                float gf = gatp[0][64 + t] + gatp[1][64 + t];
                float gg = gatp[0][128 + t] + gatp[1][128 + t];
                float go = gatp[0][192 + t] + gatp[1][192 + t];
                float c = sigf(gf) * cs[0][t] + sigf(gi) * tanhf(gg);
                cs[0][t] = c;
                hs0[t] = sigf(go) * tanhf(c);
            }
            __syncthreads();
        }
        /* layer 1: K=128 split in halves of 64 (hs0 32 + hs1 32) */
        {
            float a = (h == 0) ? (bih1[r] + bhh1[r]) : 0.0f;
            const float4* wr = (const float4*)(wih1 + (size_t)r * 64) + h * 8;
            const float4* ur = (const float4*)(whh1 + (size_t)r * 64) + h * 8;
            const float4* i4 = (const float4*)hs0 + h * 8;
            const float4* h4 = (const float4*)hs1 + h * 8;
            #pragma unroll
            for (int k4 = 0; k4 < 8; ++k4) {
                float4 wv = wr[k4];
                float4 xv = i4[k4];
                a += wv.x*xv.x + wv.y*xv.y + wv.z*xv.z + wv.w*xv.w;
                float4 uv = ur[k4];
                float4 hv = h4[k4];
                a += uv.x*hv.x + uv.y*hv.y + uv.z*hv.z + uv.w*hv.w;
            }
            gatp[h][r] = a;
            __syncthreads();
            if (t < 64) {
                float gi = gatp[0][t] + gatp[1][t];
                float gf = gatp[0][64 + t] + gatp[1][64 + t];
                float gg = gatp[0][128 + t] + gatp[1][128 + t];
                float go = gatp[0][192 + t] + gatp[1][192 + t];
                float c = sigf(gf) * cs[1][t] + sigf(gi) * tanhf(gg);
                cs[1][t] = c;
                hs1[t] = sigf(go) * tanhf(c);
            }
            __syncthreads();
        }
        /* layer 2: K=128 split in halves of 64 (hs1 32 + hs2 32) */
        {
            float a = (h == 0) ? (bih2[r] + bhh2[r]) : 0.0f;
            const float4* wr = (const float4*)(wih2 + (size_t)r * 64) + h * 8;
            const float4* ur = (const float4*)(whh2 + (size_t)r * 64) + h * 8;
            const float4* i4 = (const float4*)hs1 + h * 8;
            const float4* h4 = (const float4*)hs2 + h * 8;
            #pragma unroll
            for (int k4 = 0; k4 < 8; ++k4) {
                float4 wv = wr[k4];
                float4 xv = i4[k4];
                a += wv.x*xv.x + wv.y*xv.y + wv.z*xv.z + wv.w*xv.w;
                float4 uv = ur[k4];
                float4 hv = h4[k4];
                a += uv.x*hv.x + uv.y*hv.y + uv.z*hv.z + uv.w*hv.w;
            }
            gatp[h][r] = a;
            __syncthreads();
            if (t < 64) {
                float gi = gatp[0][t] + gatp[1][t];
                float gf = gatp[0][64 + t] + gatp[1][64 + t];
                float gg = gatp[0][128 + t] + gatp[1][128 + t];
                float go = gatp[0][192 + t] + gatp[1][192 + t];
                float c = sigf(gf) * cs[2][t] + sigf(gi) * tanhf(gg);
                cs[2][t] = c;
                hs2[t] = sigf(go) * tanhf(c);
            }
            __syncthreads();
        }
        /* attention: 8 waves, wave-cooperative rows, shfl reductions */
        {
            float q = hs2[lane];
            float mx = -3.0e38f;
            for (int p = w; p < cnt; p += 8) {
                float xv = x[(size_t)(n0 + p) * 64 + lane];
                float v = xv * q;
                v += __shfl_xor(v, 1);
                v += __shfl_xor(v, 2);
                v += __shfl_xor(v, 4);
                v += __shfl_xor(v, 8);
                v += __shfl_xor(v, 16);
                v += __shfl_xor(v, 32);
                if (lane == 0) esc[p] = v;
                if (v > mx) mx = v;
            }
            if (lane == 0) mzz[w] = mx;
            __syncthreads();
            float M = mzz[0];
            #pragma unroll
            for (int j = 1; j < 8; ++j) if (mzz[j] > M) M = mzz[j];
            float z = 0.0f;
            for (int p = t; p < cnt; p += 512) {
                float e = expf(esc[p] - M);
                esc[p] = e;
                z += e;
            }
            z += __shfl_xor(z, 1);
            z += __shfl_xor(z, 2);
            z += __shfl_xor(z, 4);
            z += __shfl_xor(z, 8);
            z += __shfl_xor(z, 16);
            z += __shfl_xor(z, 32);
            if (lane == 0) zzz[w] = z;
            __syncthreads();
            float Z = zzz[0] + zzz[1] + zzz[2] + zzz[3] + zzz[4] + zzz[5] + zzz[6] + zzz[7];
            float rd = 0.0f;
            for (int p = w; p < cnt; p += 8)
                rd += x[(size_t)(n0 + p) * 64 + lane] * esc[p];
            red8[w][lane] = rd;
            __syncthreads();
            if (t < 64) {
                float rr = red8[0][t] + red8[1][t] + red8[2][t] + red8[3][t]
                         + red8[4][t] + red8[5][t] + red8[6][t] + red8[7][t];
                rr = (cnt > 0 && Z > 0.0f) ? rr / Z : 0.0f;
                qs[t] = hs2[t];
                qs[64 + t] = rr;
            }
            __syncthreads();
        }
    }

    /* head: graphnorm -> fc1 -> bn -> relu -> fc2 -> relu (threads<128/64) */
    {
        float v = (t < 128) ? qs[t] : 0.0f;
        if (lane == 0) mzz[w] = 0.0f;
        float s1 = v, s2 = v * v;
        s1 += __shfl_xor(s1, 1); s2 += __shfl_xor(s2, 1);
        s1 += __shfl_xor(s1, 2); s2 += __shfl_xor(s2, 2);
        s1 += __shfl_xor(s1, 4); s2 += __shfl_xor(s2, 4);
        s1 += __shfl_xor(s1, 8); s2 += __shfl_xor(s2, 8);
        s1 += __shfl_xor(s1, 16); s2 += __shfl_xor(s2, 16);
        s1 += __shfl_xor(s1, 32); s2 += __shfl_xor(s2, 32);
        if (lane == 0) { mzz[w] = s1; zzz[w] = s2; }
        __syncthreads();
        float sm = mzz[0] + mzz[1];
        float sq = zzz[0] + zzz[1];
        float mu = sm * (1.0f / 128.0f);
        float var = sq * (1.0f / 128.0f) - mu * mu;
        float rs = rsqrtf(var + 1e-5f);
        if (t < 128) esc[t] = (v - mu) * rs * gn_g[t] + gn_b[t];
        __syncthreads();
        if (t < 128) {
            float y = fc1_b[t];
            const float4* wr = (const float4*)(fc1_w + (size_t)t * 128);
            #pragma unroll
            for (int k4 = 0; k4 < 32; ++k4) {
                float4 wv = wr[k4];
                float4 gv = *(const float4*)&esc[4 * k4];
                y += wv.x*gv.x + wv.y*gv.y + wv.z*gv.z + wv.w*gv.w;
            }
            y = (y - bn_m[t]) * rsqrtf(bn_v[t] + 1e-5f) * bn_g[t] + bn_b[t];
            if (y < 0.0f) y = 0.0f;
            gatp[0][t] = y;
        }
        __syncthreads();
        if (t < 64) {
            float o = fc2_b[t];
            const float4* wr = (const float4*)(fc2_w + (size_t)t * 128);
            #pragma unroll
            for (int k4 = 0; k4 < 32; ++k4) {
                float4 wv = wr[k4];
                float4 yv = *(const float4*)&gatp[0][4 * k4];
                o += wv.x*yv.x + wv.y*yv.y + wv.z*yv.z + wv.w*yv.w;
            }
            if (!(o == o)) o = 999.0f;
            else if (o < 0.0f) o = 0.0f;
            out[(size_t)g * 64 + t] = o;
        }
    }
}

extern "C" void kernel_launch(void* const* d_in, const int* in_sizes, int n_in,
                              void* d_out, int out_size, void* d_ws, size_t ws_size,
                              hipStream_t stream) {
    float* out = (float*)d_out;
    const int outBlocks = (KB * 64 + 255) / 256;

    if (n_in != 39) {
        GNNModule_9259949490279_kernel<<<outBlocks, 256, 0, stream>>>(out, 50.0f);
        return;
    }
    if (in_sizes[0] != KN * 64 || in_sizes[1] != KE || in_sizes[4] != KN) {
        GNNModule_9259949490279_kernel<<<outBlocks, 256, 0, stream>>>(out, 60.0f);
        return;
    }
    if (out_size != KB * 64) {
        GNNModule_9259949490279_kernel<<<outBlocks, 256, 0, stream>>>(out, 80.0f);
        return;
    }
    if (ws_size < O_END * 4) {
        GNNModule_9259949490279_kernel<<<outBlocks, 256, 0, stream>>>(out, 100.0f);
        return;
    }

    const float* atom = (const float*)d_in[0];
    const float* efeat = (const float*)d_in[1];
    const int* src = (const int*)d_in[2];
    const int* dst = (const int*)d_in[3];
    const int* gid = (const int*)d_in[4];
    const float* ew1[2] = {(const float*)d_in[5], (const float*)d_in[10]};
    const float* eb1[2] = {(const float*)d_in[6], (const float*)d_in[11]};
    const float* ew2[2] = {(const float*)d_in[7], (const float*)d_in[12]};
    const float* eb2[2] = {(const float*)d_in[8], (const float*)d_in[13]};
    const float* cb[2] = {(const float*)d_in[9], (const float*)d_in[14]};
    const float* ln_g = (const float*)d_in[15];
    const float* ln_b = (const float*)d_in[16];
    const float* wih0 = (const float*)d_in[17];
    const float* whh0 = (const float*)d_in[18];
    const float* bih0 = (const float*)d_in[19];
    const float* bhh0 = (const float*)d_in[20];
    const float* wih1 = (const float*)d_in[21];
    const float* whh1 = (const float*)d_in[22];
    const float* bih1 = (const float*)d_in[23];
    const float* bhh1 = (const float*)d_in[24];
    const float* wih2 = (const float*)d_in[25];
    const float* whh2 = (const float*)d_in[26];
    const float* bih2 = (const float*)d_in[27];
    const float* bhh2 = (const float*)d_in[28];
    const float* gn_g = (const float*)d_in[29];
    const float* gn_b = (const float*)d_in[30];
    const float* fc1_w = (const float*)d_in[31];
    const float* fc1_b = (const float*)d_in[32];
    const float* bn_g = (const float*)d_in[33];
    const float* bn_b = (const float*)d_in[34];
    const float* bn_m = (const float*)d_in[35];
    const float* bn_v = (const float*)d_in[36];
    const float* fc2_w = (const float*)d_in[37];
    const float* fc2_b = (const float*)d_in[38];

    float* wsf = (float*)d_ws;
    int* wsi = (int*)d_ws;
    float* buf0 = wsf + O_BUF0;
    float* buf1 = wsf + O_BUF1;
    float* deg = wsf + O_DEG;
    int* gcnt = wsi + O_GCNT;
    int* gstart = wsi + O_GST;
    int* flag = wsi + O_FLAG;
    float* Wb = wsf + O_WB;
    float* Ws = wsf + O_WS;
    float* cross = wsf + O_CROSS;
    int* rcnt = wsi + O_RCNT;
    int* region = wsi + O_REGN;

    k_init<<<2048, 256, 0, stream>>>(wsf, wsi);

    k_deg<<<KE / 256, 256, 0, stream>>>(dst, deg, flag);
    k_gcount<<<KN / 256, 256, 0, stream>>>(gid, gcnt, flag);
    k_gscan<<<1, 64, 0, stream>>>(gcnt, gstart);

    for (int l = 0; l < 2; ++l) {
        const float* xin = (l == 0) ? atom : buf0;
        float* sout = (l == 0) ? buf0 : buf1;
        int* hist = wsi + O_HIST + l * 64;
        int* cursor = wsi + O_CUR + l * 64;
        int* aoff = wsi + O_AOFF + l * 64;
        int* eorder = wsi + O_EORD + l * KEORD;
        int* rblk = wsi + O_RBLK + l * 1088;

        k_prep<<<1, 64, 0, stream>>>(ew1[l], eb1[l], cross, rcnt);
        k_mats<<<KNREG, 256, 0, stream>>>(ew1[l], eb1[l], ew2[l], eb2[l], cross, rcnt, Wb, Ws);
        k_region<<<KE / 256, 256, 0, stream>>>(efeat, cross, rcnt, region, hist);
        k_scan<<<1, 64, 0, stream>>>(hist, rcnt, aoff, rblk);
        k_scatidx<<<KE / 256, 256, 0, stream>>>(region, aoff, cursor, eorder);
        k_edge<<<KNBLK, 256, 0, stream>>>(xin, efeat, src, dst, Wb, Ws, rblk, eorder, sout);
        if (l == 0) {
            k_final0<<<KN * 64 / 256, 256, 0, stream>>>(buf0, deg, cb[0], flag);
        } else {
            k_final1ln<<<KN, 64, 0, stream>>>(buf1, deg, cb[1], ln_g, ln_b, flag);
        }
    }

    k_s2s6<<<KB, 512, 0, stream>>>(buf1, gstart,
        wih0, whh0, bih0, bhh0,
        wih1, whh1, bih1, bhh1,
        wih2, whh2, bih2, bhh2,
        gn_g, gn_b, fc1_w, fc1_b, bn_g, bn_b, bn_m, bn_v, fc2_w, fc2_b,
        out, flag);

    k_post<<<outBlocks, 256, 0, stream>>>(flag, out);
}

// Round 17
// 430.437 us; speedup vs baseline: 1.3271x; 1.0799x over previous
//
#include <hip/hip_runtime.h>

#define KN 32768
#define KE 65536
#define KB 512
#define KEPB 64
#define KNREG 33
#define KEORD (KE + KNREG * KEPB)   /* 67648 padded sorted-edge slots */
#define KNBLK (KEORD / KEPB)        /* 1057 edge blocks */

/* ---------------- workspace element offsets ---------------- */
/* zero-init zone */
#define O_BUF0 ((size_t)0)
#define O_BUF1 (O_BUF0 + (size_t)KN * 64)
#define O_DEG  (O_BUF1 + (size_t)KN * 64)
#define O_GCNT (O_DEG + KN)
#define O_GST  (O_GCNT + KB)
#define O_HIST (O_GST + KB + 8)          /* [2][64] */
#define O_CUR  (O_HIST + 128)            /* [2][64] */
#define O_FLAG (O_CUR + 128)
#define O_ZEND (O_FLAG + 64)
/* -1-init zone */
#define O_EORD ((O_ZEND + 63) & ~(size_t)63)    /* [2][KEORD] */
#define O_RBLK (O_EORD + 2 * (size_t)KEORD)     /* [2][1088] */
#define O_FEND (O_RBLK + 2 * 1088)
/* no-init zone (fully written before read) */
#define O_WB   ((O_FEND + 63) & ~(size_t)63)    /* [33][4096] */
#define O_WS   (O_WB + (size_t)KNREG * 4096)
#define O_CROSS (O_WS + (size_t)KNREG * 4096)   /* [32] */
#define O_RCNT (O_CROSS + 64)
#define O_AOFF (O_RCNT + 64)                     /* [2][64] */
#define O_REGN (O_AOFF + 128)                    /* [E] */
#define O_END  (O_REGN + KE)

/* transposed LSTM weights in dead eorder region (refilled every call).
   Layout per matrix [256][K]: wT4[k4*256 + r] = float4(W[r][4k4..4k4+3]). */
#define T_WIH0 (O_EORD)             /* 256x128 -> 32768 f32 */
#define T_WHH0 (T_WIH0 + 32768)     /* 256x64  -> 16384 */
#define T_WIH1 (T_WHH0 + 16384)
#define T_WHH1 (T_WIH1 + 16384)
#define T_WIH2 (T_WHH1 + 16384)
#define T_WHH2 (T_WIH2 + 16384)     /* end = O_EORD + 114688 <= O_RBLK */

__device__ float sigf(float x) { return 1.0f / (1.0f + expf(-x)); }

/* diagnostic fill (f32 output) */
extern "C" __global__ void GNNModule_9259949490279_kernel(float* out, float v) {
    int i = blockIdx.x * 256 + threadIdx.x;
    if (i < KB * 64) out[i] = v;
}

extern "C" __global__ void k_post(const int* flag, float* out) {
    int f = flag[0];
    if (f == 0) return;
    int i = blockIdx.x * 256 + threadIdx.x;
    if (i < KB * 64) out[i] = 300.0f + (float)f;
}

/* merged: zero-zone + (-1)-zone init in one launch */
extern "C" __global__ void k_init(float* wsf, int* wsi) {
    size_t i = (size_t)blockIdx.x * 256 + threadIdx.x;
    size_t stride = (size_t)gridDim.x * 256;
    for (size_t p = i; p < O_ZEND; p += stride) wsf[p] = 0.0f;
    for (size_t p = O_EORD + i; p < O_FEND; p += stride) wsi[p] = -1;
}

extern "C" __global__ void k_deg(const int* dst, float* deg, int* flag) {
    int e = blockIdx.x * 256 + threadIdx.x;
    if (e >= KE) return;
    int d = dst[e];
    if ((unsigned)d >= (unsigned)KN) { atomicOr(flag, 1); d = 0; }
    atomicAdd(&deg[d], 1.0f);
}

/* gid is SORTED -> a 256-node block spans few graphs; LDS histogram */
extern "C" __global__ void k_gcount(const int* gid, int* gcnt, int* flag) {
    __shared__ int lh[257];
    __shared__ int gminS;
    int t = threadIdx.x;
    int n = blockIdx.x * 256 + t;
    lh[t] = 0;
    if (t == 0) { lh[256] = 0; gminS = gid[blockIdx.x * 256]; }
    __syncthreads();
    int g = gid[n];
    if ((unsigned)g >= (unsigned)KB) { atomicOr(flag, 2); g = 0; }
    int gm = gminS;
    if ((unsigned)gm >= (unsigned)KB) gm = 0;
    int d = g - gm;
    if (d >= 0 && d < 257) atomicAdd(&lh[d], 1);
    else atomicAdd(&gcnt[g], 1);
    __syncthreads();
    if (lh[t] > 0) atomicAdd(&gcnt[gm + t], lh[t]);
    if (t == 0 && lh[256] > 0) atomicAdd(&gcnt[gm + 256], lh[256]);
}

extern "C" __global__ void k_gscan(const int* gcnt, int* gstart) {
    __shared__ int part[64];
    __shared__ int pre[64];
    int t = threadIdx.x;
    int v[8];
    int s = 0;
    int base = t * 8;
    for (int j = 0; j < 8; ++j) { v[j] = gcnt[base + j]; s += v[j]; }
    part[t] = s;
    __syncthreads();
    if (t == 0) {
        int run = 0;
        for (int i = 0; i < 64; ++i) { pre[i] = run; run += part[i]; }
    }
    __syncthreads();
    int run = pre[t];
    for (int j = 0; j < 8; ++j) { gstart[base + j] = run; run += v[j]; }
    if (t == 63) gstart[KB] = run;
}

/* ---- region machinery: exact piecewise-linear edge MLP ---- */
extern "C" __global__ void k_prep(const float* ew1, const float* eb1,
                                  float* cross, int* rcnt) {
    if (threadIdx.x != 0 || blockIdx.x != 0) return;
    float cl[32];
    int n = 0;
    for (int k = 0; k < 32; ++k) {
        float a = ew1[k], b = eb1[k];
        if (a != 0.0f) {
            float tt = -b / a;
            if (tt > 0.0f && tt < 1.0f) cl[n++] = tt;
        }
    }
    for (int i = 1; i < n; ++i) {
        float v = cl[i];
        int j = i - 1;
        while (j >= 0 && cl[j] > v) { cl[j + 1] = cl[j]; --j; }
        cl[j + 1] = v;
    }
    for (int i = 0; i < n; ++i) cross[i] = cl[i];
    *rcnt = n;
}

extern "C" __global__ __launch_bounds__(256) void k_mats(
    const float* ew1, const float* eb1, const float* ew2, const float* eb2,
    const float* cross, const int* rcnt, float* Wb, float* Ws) {
    int r = blockIdx.x;
    int n = *rcnt;
    if (r > n) return;
    float lo = (r == 0) ? 0.0f : cross[r - 1];
    float hi = (r == n) ? 1.0f : cross[r];
    float mid = 0.5f * (lo + hi);
    __shared__ float mw[32], mb[32];
    int t = threadIdx.x;
    if (t < 32) {
        bool act = (mid * ew1[t] + eb1[t]) > 0.0f;
        mw[t] = act ? ew1[t] : 0.0f;
        mb[t] = act ? eb1[t] : 0.0f;
    }
    __syncthreads();
    #pragma unroll
    for (int j = 0; j < 16; ++j) {
        int idx = j * 256 + t;
        float as = 0.0f, ab = eb2[idx];
        #pragma unroll
        for (int k4 = 0; k4 < 8; ++k4) {
            float4 w2 = *(const float4*)&ew2[(size_t)idx * 32 + 4 * k4];
            as += mw[4*k4+0]*w2.x + mw[4*k4+1]*w2.y + mw[4*k4+2]*w2.z + mw[4*k4+3]*w2.w;
            ab += mb[4*k4+0]*w2.x + mb[4*k4+1]*w2.y + mb[4*k4+2]*w2.z + mb[4*k4+3]*w2.w;
        }
        Wb[(size_t)r * 4096 + idx] = ab;
        Ws[(size_t)r * 4096 + idx] = as;
    }
}

/* LDS histogram -> <=33 global atomics per block */
extern "C" __global__ void k_region(const float* ef, const float* cross,
                                    const int* rcnt, int* region, int* hist) {
    __shared__ float lcross[32];
    __shared__ int lh[64];
    __shared__ int ln;
    int t = threadIdx.x;
    if (t == 0) ln = *rcnt;
    if (t < 64) lh[t] = 0;
    if (t >= 32 && t < 64) lcross[t - 32] = 0.0f;
    __syncthreads();
    if (t < 32 && t < ln) lcross[t] = cross[t];
    __syncthreads();
    int e = blockIdx.x * 256 + t;
    float f = ef[e];
    int n = ln, r = 0;
    for (int j = 0; j < n; ++j) r += (f > lcross[j]) ? 1 : 0;
    region[e] = r;
    atomicAdd(&lh[r], 1);
    __syncthreads();
    if (t < 64 && lh[t] > 0) atomicAdd(&hist[t], lh[t]);
}

extern "C" __global__ void k_scan(const int* hist, const int* rcnt,
                                  int* aoff, int* rblk) {
    if (threadIdx.x != 0 || blockIdx.x != 0) return;
    int R = *rcnt + 1;
    int base = 0;
    for (int r = 0; r < R; ++r) {
        aoff[r] = base * KEPB;
        int nb = (hist[r] + KEPB - 1) / KEPB;
        for (int j = 0; j < nb; ++j) rblk[base + j] = r;
        base += nb;
    }
}

/* local LDS rank + one chunk-reserving global atomic per (block,region) */
extern "C" __global__ void k_scatidx(const int* region, const int* aoff,
                                     int* cursor, int* eorder) {
    __shared__ int lcnt[64];
    __shared__ int lbase[64];
    int t = threadIdx.x;
    if (t < 64) lcnt[t] = 0;
    __syncthreads();
    int e = blockIdx.x * 256 + t;
    int r = region[e];
    int lr = atomicAdd(&lcnt[r], 1);
    __syncthreads();
    if (t < 64 && lcnt[t] > 0) lbase[t] = atomicAdd(&cursor[t], lcnt[t]);
    __syncthreads();
    eorder[aoff[r] + lbase[r] + lr] = e;
}

/* ---- edge message + scatter (HW-verified round 9, kept verbatim) ---- */
extern "C" __global__ __launch_bounds__(256) void k_edge(
    const float* x, const float* efeat, const int* src, const int* dst,
    const float* Wb, const float* Ws, const int* rblk, const int* eorder,
    float* sbuf) {
    __shared__ __align__(16) float mbuf[4096];
    __shared__ __align__(16) float msuf[4096];
    __shared__ __align__(16) float xs[4][16][64];
    int b = blockIdx.x;
    int r = rblk[b];
    if (r < 0) return;
    int t = threadIdx.x;
    const float4* gb = (const float4*)(Wb + (size_t)r * 4096);
    const float4* gs = (const float4*)(Ws + (size_t)r * 4096);
    float4* lb = (float4*)mbuf;
    float4* ls = (float4*)msuf;
    #pragma unroll
    for (int j = 0; j < 4; ++j) {
        lb[t + 256 * j] = gb[t + 256 * j];
        ls[t + 256 * j] = gs[t + 256 * j];
    }
    __syncthreads();
    int w = t >> 6, lane = t & 63;
    int base = b * KEPB + w * 16;
    int eid = (lane < 16) ? eorder[base + lane] : -1;
    float efl = 0.0f;
    int srl = 0, dsl = 0;
    if (eid >= 0) { efl = efeat[eid]; srl = src[eid]; dsl = dst[eid]; }
    unsigned long long vm = __ballot(eid >= 0);
    if ((vm & 0xFFFFull) == 0ull) return;
    float ef[16];
    int dv[16];
    #pragma unroll
    for (int s = 0; s < 16; ++s) {
        ef[s] = __shfl(efl, s);
        int sv = __shfl(srl, s);
        dv[s] = __shfl(dsl, s);
        xs[w][s][lane] = x[(size_t)sv * 64 + lane];
    }
    float acc[16];
    #pragma unroll
    for (int s = 0; s < 16; ++s) acc[s] = 0.0f;
    #pragma unroll 1
    for (int i4 = 0; i4 < 16; ++i4) {
        float wb0 = mbuf[(i4 * 4 + 0) * 64 + lane], ws0 = msuf[(i4 * 4 + 0) * 64 + lane];
        float wb1 = mbuf[(i4 * 4 + 1) * 64 + lane], ws1 = msuf[(i4 * 4 + 1) * 64 + lane];
        float wb2 = mbuf[(i4 * 4 + 2) * 64 + lane], ws2 = msuf[(i4 * 4 + 2) * 64 + lane];
        float wb3 = mbuf[(i4 * 4 + 3) * 64 + lane], ws3 = msuf[(i4 * 4 + 3) * 64 + lane];
        #pragma unroll
        for (int j = 0; j < 16; ++j) {
            float4 xv = *(const float4*)&xs[w][j][i4 * 4];
            acc[j] = fmaf(xv.x, fmaf(ef[j], ws0, wb0), acc[j]);
            acc[j] = fmaf(xv.y, fmaf(ef[j], ws1, wb1), acc[j]);
            acc[j] = fmaf(xv.z, fmaf(ef[j], ws2, wb2), acc[j]);
            acc[j] = fmaf(xv.w, fmaf(ef[j], ws3, wb3), acc[j]);
        }
    }
    #pragma unroll
    for (int j = 0; j < 16; ++j) {
        if ((vm >> j) & 1ull) atomicAdd(&sbuf[(size_t)dv[j] * 64 + lane], acc[j]);
    }
}

extern "C" __global__ void k_final0(float* s, const float* deg, const float* cb, int* flag) {
    int idx = blockIdx.x * 256 + threadIdx.x;
    int n = idx >> 6;
    int o = idx & 63;
    float d = deg[n];
    if (d < 1.0f) d = 1.0f;
    float v = s[idx] / d + cb[o];
    if (v < 0.0f) v = 0.0f;
    if (!(v == v)) { v = 0.0f; atomicOr(flag, 32); }
    s[idx] = v;
}

extern "C" __global__ void k_final1ln(float* s, const float* deg, const float* cb,
                                      const float* lg, const float* lb, int* flag) {
    __shared__ float red[64];
    int t = threadIdx.x;
    int n = blockIdx.x;
    float d = deg[n];
    if (d < 1.0f) d = 1.0f;
    float v = s[(size_t)n * 64 + t] / d + cb[t];
    if (v < 0.0f) v = 0.0f;
    red[t] = v;
    __syncthreads();
    for (int m = 32; m >= 1; m >>= 1) {
        if (t < m) red[t] += red[t + m];
        __syncthreads();
    }
    float mu = red[0] * (1.0f / 64.0f);
    __syncthreads();
    red[t] = v * v;
    __syncthreads();
    for (int m = 32; m >= 1; m >>= 1) {
        if (t < m) red[t] += red[t + m];
        __syncthreads();
    }
    float var = red[0] * (1.0f / 64.0f) - mu * mu;
    float rs = rsqrtf(var + 1e-5f);
    float r = (v - mu) * rs * lg[t] + lb[t];
    if (!(r == r)) { r = 0.0f; atomicOr(flag, 8); }
    s[(size_t)n * 64 + t] = r;
}

/* one-time weight transpose into float4-column layout (R=256 always):
   dst[k4*256 + r] = float4(src[r][4k4 .. 4k4+3]) */
extern "C" __global__ void k_tw(const float* src, float4* dst, int K) {
    int idx = blockIdx.x * 256 + threadIdx.x;
    int total = 256 * (K >> 2);
    if (idx >= total) return;
    int r = idx & 255;
    int k4 = idx >> 8;
    const float* s = src + (size_t)r * K + 4 * k4;
    dst[idx] = make_float4(s[0], s[1], s[2], s[3]);
}

/* ---- Set2Set + head v7: round-16 k-split structure (512 thr, VGPR~64,
   occupancy 40%) + COALESCED transposed weight columns ---- */
extern "C" __global__ __launch_bounds__(512) void k_s2s7(
    const float* x, const int* gstart,
    const float4* wT0, const float4* uT0, const float* bih0, const float* bhh0,
    const float4* wT1, const float4* uT1, const float* bih1, const float* bhh1,
    const float4* wT2, const float4* uT2, const float* bih2, const float* bhh2,
    const float* gn_g, const float* gn_b,
    const float* fc1_w, const float* fc1_b,
    const float* bn_g, const float* bn_b, const float* bn_m, const float* bn_v,
    const float* fc2_w, const float* fc2_b,
    float* out, int* flag) {
    __shared__ __align__(16) float qs[128];
    __shared__ __align__(16) float hs0[64];
    __shared__ __align__(16) float hs1[64];
    __shared__ __align__(16) float hs2[64];
    __shared__ __align__(16) float cs[3][64];
    __shared__ __align__(16) float gatp[2][256];
    __shared__ __align__(16) float esc[1024];
    __shared__ __align__(16) float red8[8][64];
    __shared__ float mzz[8], zzz[8];
    int t = threadIdx.x;            /* 0..511 */
    int g = blockIdx.x;
    int r = t & 255, h = t >> 8;    /* gate row, k-half */
    int w = t >> 6, lane = t & 63;  /* wave 0..7 */

    if (t < 128) qs[t] = 0.0f;
    if (t < 64) {
        hs0[t] = 0.0f; hs1[t] = 0.0f; hs2[t] = 0.0f;
        cs[0][t] = 0.0f; cs[1][t] = 0.0f; cs[2][t] = 0.0f;
    }
    __syncthreads();

    int n0 = gstart[g];
    int n1 = gstart[g + 1];
    if (n0 < 0) n0 = 0;
    if (n0 > KN) n0 = KN;
    if (n1 < n0) n1 = n0;
    if (n1 > KN) n1 = KN;
    int cnt = n1 - n0;
    if (cnt > 1024) { cnt = 1024; if (t == 0) atomicOr(flag, 16); }

    for (int it = 0; it < 6; ++it) {
        /* layer 0: K-half h covers qs[64h..64h+63] + hs0[32h..32h+31];
           coalesced columns wT0[(h*16+k4)*256 + r] */
        {
            float a = (h == 0) ? (bih0[r] + bhh0[r]) : 0.0f;
            const float4* wc = wT0 + (size_t)(h * 16) * 256 + r;
            const float4* q4 = (const float4*)qs + h * 16;
            #pragma unroll 8
            for (int k4 = 0; k4 < 16; ++k4) {
                float4 wv = wc[k4 * 256];
                float4 xv = q4[k4];
                a += wv.x*xv.x + wv.y*xv.y + wv.z*xv.z + wv.w*xv.w;
            }
            const float4* uc = uT0 + (size_t)(h * 8) * 256 + r;
            const float4* h4 = (const float4*)hs0 + h * 8;
            #pragma unroll 8
            for (int k4 = 0; k4 < 8; ++k4) {
                float4 wv = uc[k4 * 256];
                float4 hv = h4[k4];
                a += wv.x*hv.x + wv.y*hv.y + wv.z*hv.z + wv.w*hv.w;
            }
            gatp[h][r] = a;
            __syncthreads();
            if (t < 64) {
                float gi = gatp[0][t] + gatp[1][t];
                float gf = gatp[0][64 + t] + gatp[1][64 + t];
                float gg = gatp[0][128 + t] + gatp[1][128 + t];
                float go = gatp[0][192 + t] + gatp[1][192 + t];
                float c = sigf(gf) * cs[0][t] + sigf(gi) * tanhf(gg);
                cs[0][t] = c;
                hs0[t] = sigf(go) * tanhf(c);
            }
            __syncthreads();
        }
        /* layer 1 */
        {
            float a = (h == 0) ? (bih1[r] + bhh1[r]) : 0.0f;
            const float4* wc = wT1 + (size_t)(h * 8) * 256 + r;
            const float4* uc = uT1 + (size_t)(h * 8) * 256 + r;
            const float4* i4 = (const float4*)hs0 + h * 8;
            const float4* h4 = (const float4*)hs1 + h * 8;
            #pragma unroll 8
            for (int k4 = 0; k4 < 8; ++k4) {
                float4 wv = wc[k4 * 256];
                float4 xv = i4[k4];
                a += wv.x*xv.x + wv.y*xv.y + wv.z*xv.z + wv.w*xv.w;
                float4 uv = uc[k4 * 256];
                float4 hv = h4[k4];
                a += uv.x*hv.x + uv.y*hv.y + uv.z*hv.z + uv.w*hv.w;
            }
            gatp[h][r] = a;
            __syncthreads();
            if (t < 64) {
                float gi = gatp[0][t] + gatp[1][t];
                float gf = gatp[0][64 + t] + gatp[1][64 + t];
                float gg = gatp[0][128 + t] + gatp[1][128 + t];
                float go = gatp[0][192 + t] + gatp[1][192 + t];
                float c = sigf(gf) * cs[1][t] + sigf(gi) * tanhf(gg);
                cs[1][t] = c;
                hs1[t] = sigf(go) * tanhf(c);
            }
            __syncthreads();
        }
        /* layer 2 */
        {
            float a = (h == 0) ? (bih2[r] + bhh2[r]) : 0.0f;
            const float4* wc = wT2 + (size_t)(h * 8) * 256 + r;
            const float4* uc = uT2 + (size_t)(h * 8) * 256 + r;
            const float4* i4 = (const float4*)hs1 + h * 8;
            const float4* h4 = (const float4*)hs2 + h * 8;
            #pragma unroll 8
            for (int k4 = 0; k4 < 8; ++k4) {
                float4 wv = wc[k4 * 256];
                float4 xv = i4[k4];
                a += wv.x*xv.x + wv.y*xv.y + wv.z*xv.z + wv.w*xv.w;
                float4 uv = uc[k4 * 256];
                float4 hv = h4[k4];
                a += uv.x*hv.x + uv.y*hv.y + uv.z*hv.z + uv.w*hv.w;
            }
            gatp[h][r] = a;
            __syncthreads();
            if (t < 64) {
                float gi = gatp[0][t] + gatp[1][t];
                float gf = gatp[0][64 + t] + gatp[1][64 + t];
                float gg = gatp[0][128 + t] + gatp[1][128 + t];
                float go = gatp[0][192 + t] + gatp[1][192 + t];
                float c = sigf(gf) * cs[2][t] + sigf(gi) * tanhf(gg);
                cs[2][t] = c;
                hs2[t] = sigf(go) * tanhf(c);
            }
            __syncthreads();
        }
        /* attention: 8 waves, wave-cooperative rows, shfl reductions */
        {
            float q = hs2[lane];
            float mx = -3.0e38f;
            for (int p = w; p < cnt; p += 8) {
                float xv = x[(size_t)(n0 + p) * 64 + lane];
                float v = xv * q;
                v += __shfl_xor(v, 1);
                v += __shfl_xor(v, 2);
                v += __shfl_xor(v, 4);
                v += __shfl_xor(v, 8);
                v += __shfl_xor(v, 16);
                v += __shfl_xor(v, 32);
                if (lane == 0) esc[p] = v;
                if (v > mx) mx = v;
            }
            if (lane == 0) mzz[w] = mx;
            __syncthreads();
            float M = mzz[0];
            #pragma unroll
            for (int j = 1; j < 8; ++j) if (mzz[j] > M) M = mzz[j];
            float z = 0.0f;
            for (int p = t; p < cnt; p += 512) {
                float e = expf(esc[p] - M);
                esc[p] = e;
                z += e;
            }
            z += __shfl_xor(z, 1);
            z += __shfl_xor(z, 2);
            z += __shfl_xor(z, 4);
            z += __shfl_xor(z, 8);
            z += __shfl_xor(z, 16);
            z += __shfl_xor(z, 32);
            if (lane == 0) zzz[w] = z;
            __syncthreads();
            float Z = zzz[0] + zzz[1] + zzz[2] + zzz[3] + zzz[4] + zzz[5] + zzz[6] + zzz[7];
            float rd = 0.0f;
            for (int p = w; p < cnt; p += 8)
                rd += x[(size_t)(n0 + p) * 64 + lane] * esc[p];
            red8[w][lane] = rd;
            __syncthreads();
            if (t < 64) {
                float rr = red8[0][t] + red8[1][t] + red8[2][t] + red8[3][t]
                         + red8[4][t] + red8[5][t] + red8[6][t] + red8[7][t];
                rr = (cnt > 0 && Z > 0.0f) ? rr / Z : 0.0f;
                qs[t] = hs2[t];
                qs[64 + t] = rr;
            }
            __syncthreads();
        }
    }

    /* head: graphnorm -> fc1 -> bn -> relu -> fc2 -> relu */
    {
        float v = (t < 128) ? qs[t] : 0.0f;
        if (lane == 0) mzz[w] = 0.0f;
        float s1 = v, s2 = v * v;
        s1 += __shfl_xor(s1, 1); s2 += __shfl_xor(s2, 1);
        s1 += __shfl_xor(s1, 2); s2 += __shfl_xor(s2, 2);
        s1 += __shfl_xor(s1, 4); s2 += __shfl_xor(s2, 4);
        s1 += __shfl_xor(s1, 8); s2 += __shfl_xor(s2, 8);
        s1 += __shfl_xor(s1, 16); s2 += __shfl_xor(s2, 16);
        s1 += __shfl_xor(s1, 32); s2 += __shfl_xor(s2, 32);
        if (lane == 0) { mzz[w] = s1; zzz[w] = s2; }
        __syncthreads();
        float sm = mzz[0] + mzz[1];
        float sq = zzz[0] + zzz[1];
        float mu = sm * (1.0f / 128.0f);
        float var = sq * (1.0f / 128.0f) - mu * mu;
        float rs = rsqrtf(var + 1e-5f);
        if (t < 128) esc[t] = (v - mu) * rs * gn_g[t] + gn_b[t];
        __syncthreads();
        if (t < 128) {
            float y = fc1_b[t];
            const float4* wr = (const float4*)(fc1_w + (size_t)t * 128);
            #pragma unroll
            for (int k4 = 0; k4 < 32; ++k4) {
                float4 wv = wr[k4];
                float4 gv = *(const float4*)&esc[4 * k4];
                y += wv.x*gv.x + wv.y*gv.y + wv.z*gv.z + wv.w*gv.w;
            }
            y = (y - bn_m[t]) * rsqrtf(bn_v[t] + 1e-5f) * bn_g[t] + bn_b[t];
            if (y < 0.0f) y = 0.0f;
            gatp[0][t] = y;
        }
        __syncthreads();
        if (t < 64) {
            float o = fc2_b[t];
            const float4* wr = (const float4*)(fc2_w + (size_t)t * 128);
            #pragma unroll
            for (int k4 = 0; k4 < 32; ++k4) {
                float4 wv = wr[k4];
                float4 yv = *(const float4*)&gatp[0][4 * k4];
                o += wv.x*yv.x + wv.y*yv.y + wv.z*yv.z + wv.w*yv.w;
            }
            if (!(o == o)) o = 999.0f;
            else if (o < 0.0f) o = 0.0f;
            out[(size_t)g * 64 + t] = o;
        }
    }
}

extern "C" void kernel_launch(void* const* d_in, const int* in_sizes, int n_in,
                              void* d_out, int out_size, void* d_ws, size_t ws_size,
                              hipStream_t stream) {
    float* out = (float*)d_out;
    const int outBlocks = (KB * 64 + 255) / 256;

    if (n_in != 39) {
        GNNModule_9259949490279_kernel<<<outBlocks, 256, 0, stream>>>(out, 50.0f);
        return;
    }
    if (in_sizes[0] != KN * 64 || in_sizes[1] != KE || in_sizes[4] != KN) {
        GNNModule_9259949490279_kernel<<<outBlocks, 256, 0, stream>>>(out, 60.0f);
        return;
    }
    if (out_size != KB * 64) {
        GNNModule_9259949490279_kernel<<<outBlocks, 256, 0, stream>>>(out, 80.0f);
        return;
    }
    if (ws_size < O_END * 4) {
        GNNModule_9259949490279_kernel<<<outBlocks, 256, 0, stream>>>(out, 100.0f);
        return;
    }

    const float* atom = (const float*)d_in[0];
    const float* efeat = (const float*)d_in[1];
    const int* src = (const int*)d_in[2];
    const int* dst = (const int*)d_in[3];
    const int* gid = (const int*)d_in[4];
    const float* ew1[2] = {(const float*)d_in[5], (const float*)d_in[10]};
    const float* eb1[2] = {(const float*)d_in[6], (const float*)d_in[11]};
    const float* ew2[2] = {(const float*)d_in[7], (const float*)d_in[12]};
    const float* eb2[2] = {(const float*)d_in[8], (const float*)d_in[13]};
    const float* cb[2] = {(const float*)d_in[9], (const float*)d_in[14]};
    const float* ln_g = (const float*)d_in[15];
    const float* ln_b = (const float*)d_in[16];
    const float* wih0 = (const float*)d_in[17];
    const float* whh0 = (const float*)d_in[18];
    const float* bih0 = (const float*)d_in[19];
    const float* bhh0 = (const float*)d_in[20];
    const float* wih1 = (const float*)d_in[21];
    const float* whh1 = (const float*)d_in[22];
    const float* bih1 = (const float*)d_in[23];
    const float* bhh1 = (const float*)d_in[24];
    const float* wih2 = (const float*)d_in[25];
    const float* whh2 = (const float*)d_in[26];
    const float* bih2 = (const float*)d_in[27];
    const float* bhh2 = (const float*)d_in[28];
    const float* gn_g = (const float*)d_in[29];
    const float* gn_b = (const float*)d_in[30];
    const float* fc1_w = (const float*)d_in[31];
    const float* fc1_b = (const float*)d_in[32];
    const float* bn_g = (const float*)d_in[33];
    const float* bn_b = (const float*)d_in[34];
    const float* bn_m = (const float*)d_in[35];
    const float* bn_v = (const float*)d_in[36];
    const float* fc2_w = (const float*)d_in[37];
    const float* fc2_b = (const float*)d_in[38];

    float* wsf = (float*)d_ws;
    int* wsi = (int*)d_ws;
    float* buf0 = wsf + O_BUF0;
    float* buf1 = wsf + O_BUF1;
    float* deg = wsf + O_DEG;
    int* gcnt = wsi + O_GCNT;
    int* gstart = wsi + O_GST;
    int* flag = wsi + O_FLAG;
    float* Wb = wsf + O_WB;
    float* Ws = wsf + O_WS;
    float* cross = wsf + O_CROSS;
    int* rcnt = wsi + O_RCNT;
    int* region = wsi + O_REGN;

    k_init<<<2048, 256, 0, stream>>>(wsf, wsi);

    k_deg<<<KE / 256, 256, 0, stream>>>(dst, deg, flag);
    k_gcount<<<KN / 256, 256, 0, stream>>>(gid, gcnt, flag);
    k_gscan<<<1, 64, 0, stream>>>(gcnt, gstart);

    for (int l = 0; l < 2; ++l) {
        const float* xin = (l == 0) ? atom : buf0;
        float* sout = (l == 0) ? buf0 : buf1;
        int* hist = wsi + O_HIST + l * 64;
        int* cursor = wsi + O_CUR + l * 64;
        int* aoff = wsi + O_AOFF + l * 64;
        int* eorder = wsi + O_EORD + l * KEORD;
        int* rblk = wsi + O_RBLK + l * 1088;

        k_prep<<<1, 64, 0, stream>>>(ew1[l], eb1[l], cross, rcnt);
        k_mats<<<KNREG, 256, 0, stream>>>(ew1[l], eb1[l], ew2[l], eb2[l], cross, rcnt, Wb, Ws);
        k_region<<<KE / 256, 256, 0, stream>>>(efeat, cross, rcnt, region, hist);
        k_scan<<<1, 64, 0, stream>>>(hist, rcnt, aoff, rblk);
        k_scatidx<<<KE / 256, 256, 0, stream>>>(region, aoff, cursor, eorder);
        k_edge<<<KNBLK, 256, 0, stream>>>(xin, efeat, src, dst, Wb, Ws, rblk, eorder, sout);
        if (l == 0) {
            k_final0<<<KN * 64 / 256, 256, 0, stream>>>(buf0, deg, cb[0], flag);
        } else {
            k_final1ln<<<KN, 64, 0, stream>>>(buf1, deg, cb[1], ln_g, ln_b, flag);
        }
    }

    /* transpose LSTM weights into the now-dead eorder region */
    float4* tw0 = (float4*)(wsf + T_WIH0);
    float4* tu0 = (float4*)(wsf + T_WHH0);
    float4* tw1 = (float4*)(wsf + T_WIH1);
    float4* tu1 = (float4*)(wsf + T_WHH1);
    float4* tw2 = (float4*)(wsf + T_WIH2);
    float4* tu2 = (float4*)(wsf + T_WHH2);
    k_tw<<<32, 256, 0, stream>>>(wih0, tw0, 128);
    k_tw<<<16, 256, 0, stream>>>(whh0, tu0, 64);
    k_tw<<<16, 256, 0, stream>>>(wih1, tw1, 64);
    k_tw<<<16, 256, 0, stream>>>(whh1, tu1, 64);
    k_tw<<<16, 256, 0, stream>>>(wih2, tw2, 64);
    k_tw<<<16, 256, 0, stream>>>(whh2, tu2, 64);

    k_s2s7<<<KB, 512, 0, stream>>>(buf1, gstart,
        tw0, tu0, bih0, bhh0,
        tw1, tu1, bih1, bhh1,
        tw2, tu2, bih2, bhh2,
        gn_g, gn_b, fc1_w, fc1_b, bn_g, bn_b, bn_m, bn_v, fc2_w, fc2_b,
        out, flag);

    k_post<<<outBlocks, 256, 0, stream>>>(flag, out);
}